// Round 1
// 443.513 us; speedup vs baseline: 1.1644x; 1.1644x over previous
//
#include <hip/hip_runtime.h>
#include <stdint.h>

// LightMetaPolicy fused kernel, round 6:
//  - 512-thread blocks (8 waves), __launch_bounds__(512,4) -> 16 waves/CU
//    (round-5 was 8 waves/CU, Occupancy 23%, VALUBusy 48% => latency-bound).
//  - Phase 3b (pooled@Wmlp^T + gelu) and 3c logits (H@Wp2^T) moved to MFMA
//    with split-bf16 activations (phase-1 recipe) -- was ~60% of VALU work.
//  - Wmlp/Whead weights pre-fragmented to bf16 MFMA B-layout in setup_kernel
//    (ws tables); per-block f32->bf16 staging loop deleted.
//  - pooled / H are written directly in MFMA A-fragment layout (hi/lo bf16
//    tables) so fragment loads are contiguous uint4 LDS reads (conflict-free).
//
// Folds: R = x@(Wr@Wq)^T + (Wr@bq+br); pooled via column-sum of masked A.
// E LDS per agent-row: cols [0:32)=Q, [32:64)=K, [64:96)=R, [96:160)=V
//
// MFMA 16x16x32 bf16 layouts (m89-verified):
//   A: lane holds A[m=lane&15][k=quad*8+j], j=0..7  (quad=lane>>4)
//   B: lane holds B[k=quad*8+j][n=lane&15]
//   C: lane reg r holds C[row=quad*4+r][col=lane&15]

typedef __attribute__((ext_vector_type(8))) short bf16x8;
typedef __attribute__((ext_vector_type(4))) float f32x4;

#define ESTR 162   // E stride (shorts): 81 dwords, odd -> conflict-free rows

#define WF1_OFF 0      // phase-1 B-frags: 20 frags * 64 lanes * 16B = 20480
#define BC_OFF  20480  // bcat f32[160] = 640
#define WF2_OFF 21120  // phase-3b B-frags: 16 frags * 1024B = 16384
#define WF3_OFF 37504  // phase-3c B-frags:  8 frags * 1024B = 8192
// ws total: 45696 B

__device__ __forceinline__ float b2f_lo(unsigned int pk) {
  union { unsigned int i; float f; } v; v.i = pk << 16; return v.f;
}
__device__ __forceinline__ float b2f_hi(unsigned int pk) {
  union { unsigned int i; float f; } v; v.i = pk & 0xffff0000u; return v.f;
}
__device__ __forceinline__ float b2f(unsigned short u) {
  union { unsigned int i; float f; } v; v.i = ((unsigned int)u) << 16; return v.f;
}
__device__ __forceinline__ unsigned short f2b(float f) {
  union { float f; unsigned int i; } v; v.f = f;
  unsigned int u = v.i;
  return (unsigned short)((u + 0x7fffu + ((u >> 16) & 1u)) >> 16);  // RNE
}

// ---------------------------------------------------------------- setup ----
__global__ void setup_kernel(const float* __restrict__ Wk,
                             const float* __restrict__ bk,
                             const float* __restrict__ Wq,
                             const float* __restrict__ bq,
                             const float* __restrict__ Wv,
                             const float* __restrict__ bv,
                             const float* __restrict__ Wr,
                             const float* __restrict__ br,
                             const float* __restrict__ Wp1,
                             const float* __restrict__ Wh1,
                             const float* __restrict__ Wp2,
                             char* __restrict__ ws) {
  __shared__ float Wrp[32 * 64];  // Wr' = Wr @ Wq
  const int t = threadIdx.x;
  for (int i = t; i < 32 * 64; i += 256) {
    int rr = i >> 6, d = i & 63;
    float acc = 0.f;
    for (int m = 0; m < 32; ++m) acc += Wr[rr * 32 + m] * Wq[m * 64 + d];
    Wrp[i] = acc;
  }
  __syncthreads();

  unsigned short* wf1 = (unsigned short*)(ws + WF1_OFF);
  float* bc = (float*)(ws + BC_OFF);
  unsigned short* wf2 = (unsigned short*)(ws + WF2_OFF);
  unsigned short* wf3 = (unsigned short*)(ws + WF3_OFF);

  // phase-1 B-frags: fs = nt*2+s (nt 0..9, s 0..1)
  for (int i = t; i < 20 * 64 * 8; i += 256) {
    int j = i & 7, l = (i >> 3) & 63, fs = i >> 9;
    int nt = fs >> 1, s = fs & 1;
    int r = nt * 16 + (l & 15);            // output channel (Wcat row)
    int k = s * 32 + ((l >> 4) & 3) * 8 + j;
    float w;
    if (r < 32)      w = Wq[r * 64 + k];
    else if (r < 64) w = Wk[(r - 32) * 64 + k];
    else if (r < 96) w = Wrp[(r - 64) * 64 + k];
    else             w = Wv[(r - 96) * 64 + k];
    wf1[i] = f2b(w);
  }
  if (t < 160) {
    int r = t;
    float v;
    if (r < 32)      v = bq[r];
    else if (r < 64) v = bk[r - 32];
    else if (r < 96) {
      int rr = r - 64;
      float acc = br[rr];
      for (int m = 0; m < 32; ++m) acc += Wr[rr * 32 + m] * bq[m];
      v = acc;
    } else            v = bv[r - 96];
    bc[r] = v;
  }
  // phase-3b B-frags (Wmlp = [Wp1;Wh1], 128x64): fs = nt*2+s, nt 0..7
  for (int i = t; i < 16 * 64 * 8; i += 256) {
    int j = i & 7, l = (i >> 3) & 63, fs = i >> 9;
    int nt = fs >> 1, s = fs & 1;
    int n = nt * 16 + (l & 15);
    int k = s * 32 + ((l >> 4) & 3) * 8 + j;
    float wv = (n < 64) ? Wp1[n * 64 + k] : Wh1[(n - 64) * 64 + k];
    wf2[i] = f2b(wv);
  }
  // phase-3c B-frags (Wp2, 50x64 zero-padded to 64): fs = nt*2+s, nt 0..3
  for (int i = t; i < 8 * 64 * 8; i += 256) {
    int j = i & 7, l = (i >> 3) & 63, fs = i >> 9;
    int nt = fs >> 1, s = fs & 1;
    int n = nt * 16 + (l & 15);
    int k = s * 32 + ((l >> 4) & 3) * 8 + j;
    float wv = (n < 50) ? Wp2[n * 64 + k] : 0.f;
    wf3[i] = f2b(wv);
  }
}

// ----------------------------------------------------------------- main ----
__global__ __launch_bounds__(512, 4)
void policy_kernel(const float* __restrict__ x,
                   const char* __restrict__ ws,
                   const float* __restrict__ bp1,
                   const float* __restrict__ bp2,
                   const float* __restrict__ bh1,
                   const float* __restrict__ bh2,
                   const float* __restrict__ Wh2,
                   float* __restrict__ out, int B) {
  // 32 batches/block = 160 agent-rows. 8 waves.
  __shared__ __align__(16) unsigned short Els[160 * ESTR];  // 51,840 B
  __shared__ float maskLs[160];                             // 640 B
  __shared__ float asw[32 * 25];                            // 3,200 B
  // pooled in MFMA A-frag layout, split bf16: frag f = (mt*2+s), f 0..3
  __shared__ __align__(16) unsigned short pHi[4 * 64 * 8];  // 4,096 B
  __shared__ __align__(16) unsigned short pLo[4 * 64 * 8];  // 4,096 B
  // total 63,872 B -> 2 blocks/CU (16 waves)

  const int t = threadIdx.x;
  const int w = t >> 6, lane = t & 63;
  const int l15 = lane & 15, quad = lane >> 4;

  const uint4* wf1 = (const uint4*)(ws + WF1_OFF);
  const float* bc = (const float*)(ws + BC_OFF);
  const uint4* wf2 = (const uint4*)(ws + WF2_OFF);
  const uint4* wf3 = (const uint4*)(ws + WF3_OFF);

  // ---- phase 0: agent mask (also pre-warms the x tile in L1/L2) ---------
  if (t < 160) {
    long row = (long)blockIdx.x * 160 + t;
    const float4* xp = (const float4*)(x + row * 64);
    float ms = 0.f;
#pragma unroll
    for (int i = 0; i < 16; ++i) {
      float4 v = xp[i];
      ms += fabsf(v.x) + fabsf(v.y) + fabsf(v.z) + fabsf(v.w);
    }
    maskLs[t] = (ms > 0.01f) ? 1.f : 0.f;
  }

  // ---- phase 1: E = x @ Wcat^T + bcat via MFMA, split-bf16 x ------------
  // 100 tiles (m 0..9, n 0..9) over 8 waves, m-contiguous ranges so the
  // split-bf16 x conversion amortizes (2-3 m-values per wave).
  {
    union { uint4 u; bf16x8 v; } ah0, ah1, al0, al1;  // hi/lo x k-halves
    int mcur = -1;
    const int start = (w < 4) ? w * 13 : 52 + (w - 4) * 12;
    const int cnt = (w < 4) ? 13 : 12;
    for (int ti = 0; ti < cnt; ++ti) {
      int tt = start + ti;
      int m = tt / 10, n = tt - m * 10;
      if (m != mcur) {
        mcur = m;
        long row = (long)blockIdx.x * 160 + m * 16 + l15;
        const float* xr = x + row * 64 + quad * 8;
        float xv[16];
        *(float4*)(xv + 0)  = *(const float4*)(xr);
        *(float4*)(xv + 4)  = *(const float4*)(xr + 4);
        *(float4*)(xv + 8)  = *(const float4*)(xr + 32);
        *(float4*)(xv + 12) = *(const float4*)(xr + 36);
        unsigned int hw[8], lw[8];
#pragma unroll
        for (int i = 0; i < 8; ++i) {
          unsigned short h0 = f2b(xv[2 * i]);
          unsigned short h1 = f2b(xv[2 * i + 1]);
          float r0 = xv[2 * i]     - b2f(h0);
          float r1 = xv[2 * i + 1] - b2f(h1);
          hw[i] = (unsigned int)h0 | ((unsigned int)h1 << 16);
          lw[i] = (unsigned int)f2b(r0) | ((unsigned int)f2b(r1) << 16);
        }
        ah0.u = make_uint4(hw[0], hw[1], hw[2], hw[3]);
        ah1.u = make_uint4(hw[4], hw[5], hw[6], hw[7]);
        al0.u = make_uint4(lw[0], lw[1], lw[2], lw[3]);
        al1.u = make_uint4(lw[4], lw[5], lw[6], lw[7]);
      }
      union { uint4 u; bf16x8 v; } b0, b1;
      b0.u = wf1[(n * 2 + 0) * 64 + lane];
      b1.u = wf1[(n * 2 + 1) * 64 + lane];
      f32x4 acc = {0.f, 0.f, 0.f, 0.f};
      acc = __builtin_amdgcn_mfma_f32_16x16x32_bf16(al0.v, b0.v, acc, 0, 0, 0);
      acc = __builtin_amdgcn_mfma_f32_16x16x32_bf16(al1.v, b1.v, acc, 0, 0, 0);
      acc = __builtin_amdgcn_mfma_f32_16x16x32_bf16(ah0.v, b0.v, acc, 0, 0, 0);
      acc = __builtin_amdgcn_mfma_f32_16x16x32_bf16(ah1.v, b1.v, acc, 0, 0, 0);
      float bias = bc[n * 16 + l15];
      int r0 = m * 16 + quad * 4;
      int col = n * 16 + l15;
#pragma unroll
      for (int r = 0; r < 4; ++r)
        Els[(r0 + r) * ESTR + col] = f2b(acc[r] + bias);
    }
  }
  __syncthreads();

  // ---- phase 2: S = scale*(Q·K + R·R), softmax, mask --------------------
  if (t < 160) {
    const int b = t / 5, q = t - 5 * b;
    float qrv[64];
#pragma unroll
    for (int j = 0; j < 16; ++j) {
      unsigned int pk = *(const unsigned int*)&Els[t * ESTR + 2 * j];
      qrv[2 * j] = b2f_lo(pk); qrv[2 * j + 1] = b2f_hi(pk);
    }
#pragma unroll
    for (int j = 0; j < 16; ++j) {
      unsigned int pk = *(const unsigned int*)&Els[t * ESTR + 64 + 2 * j];
      qrv[32 + 2 * j] = b2f_lo(pk); qrv[33 + 2 * j] = b2f_hi(pk);
    }
    float sc[5];
#pragma unroll
    for (int k = 0; k < 5; ++k) {
      const unsigned short* er = &Els[(5 * b + k) * ESTR];
      float ax = 0.f, ay = 0.f;
#pragma unroll
      for (int j = 0; j < 16; ++j) {
        unsigned int pk = *(const unsigned int*)&er[32 + 2 * j];
        ax = __builtin_fmaf(qrv[2 * j],     b2f_lo(pk), ax);
        ay = __builtin_fmaf(qrv[2 * j + 1], b2f_hi(pk), ay);
      }
#pragma unroll
      for (int j = 0; j < 16; ++j) {
        unsigned int pk = *(const unsigned int*)&er[64 + 2 * j];
        ax = __builtin_fmaf(qrv[32 + 2 * j], b2f_lo(pk), ax);
        ay = __builtin_fmaf(qrv[33 + 2 * j], b2f_hi(pk), ay);
      }
      sc[k] = (ax + ay) * 0.17677669529663689f;
    }
    float mx = sc[0];
#pragma unroll
    for (int k = 1; k < 5; ++k) mx = fmaxf(mx, sc[k]);
    float p[5], ps = 0.f;
#pragma unroll
    for (int k = 0; k < 5; ++k) { p[k] = __expf(sc[k] - mx); ps += p[k]; }
    float mscale = maskLs[t] / ps;
#pragma unroll
    for (int k = 0; k < 5; ++k) asw[b * 25 + q * 5 + k] = p[k] * mscale;
  }
  __syncthreads();

  // ---- phase 3a: pooled = inv * sum_k w[k]*V[k][:], write as A-frags ----
  for (int i = t; i < 32 * 64; i += 512) {
    int b = i >> 6, d = i & 63;
    const float* aw = &asw[b * 25];
    float wk[5] = {0.f, 0.f, 0.f, 0.f, 0.f};
#pragma unroll
    for (int q2 = 0; q2 < 5; ++q2)
#pragma unroll
      for (int k = 0; k < 5; ++k) wk[k] += aw[q2 * 5 + k];
    float msumB = maskLs[b * 5] + maskLs[b * 5 + 1] + maskLs[b * 5 + 2] +
                  maskLs[b * 5 + 3] + maskLs[b * 5 + 4];
    float inv = 1.0f / (msumB + 1e-8f);
    float acc = 0.f;
#pragma unroll
    for (int k = 0; k < 5; ++k)
      acc += wk[k] * b2f(Els[(5 * b + k) * ESTR + 96 + d]);
    float pv = acc * inv;
    unsigned short hi = f2b(pv);
    unsigned short lo = f2b(pv - b2f(hi));
    // A-frag position: frag (b>>4)*2 + (d>>5), lane ((d>>3)&3)*16 + (b&15),
    // element d&7  (A: lane holds A[m=lane&15][k=quad*8+j])
    int fi = (((b >> 4) * 2 + (d >> 5)) * 64 + ((d >> 3) & 3) * 16 + (b & 15)) * 8
             + (d & 7);
    pHi[fi] = hi; pLo[fi] = lo;
  }
  __syncthreads();

  // ---- phase 3b: H = gelu(pooled @ Wmlp^T + bias) via MFMA --------------
  // 16 tiles (mt 0..1, nt 0..7); wave w: mt=w>>2, nt=(w&3)*2+{0,1}.
  // H cols <64 written as split-bf16 A-frags (for 3c MFMA); cols >=64 as
  // f32 rows (value head). All land in the now-dead Els region.
  {
    unsigned short* HHi = (unsigned short*)Els;                    // 4,096 B
    unsigned short* HLo = (unsigned short*)((char*)Els + 4096);    // 4,096 B
    float* Hv = (float*)((char*)Els + 8192);                       // [32][65] f32
    const int mt = w >> 2;
    union { uint4 u; bf16x8 v; } aH0, aH1, aL0, aL1;
    aH0.u = *(const uint4*)&pHi[((mt * 2 + 0) * 64 + lane) * 8];
    aH1.u = *(const uint4*)&pHi[((mt * 2 + 1) * 64 + lane) * 8];
    aL0.u = *(const uint4*)&pLo[((mt * 2 + 0) * 64 + lane) * 8];
    aL1.u = *(const uint4*)&pLo[((mt * 2 + 1) * 64 + lane) * 8];
#pragma unroll
    for (int tI = 0; tI < 2; ++tI) {
      int nt = (w & 3) * 2 + tI;
      union { uint4 u; bf16x8 v; } b0, b1;
      b0.u = wf2[(nt * 2 + 0) * 64 + lane];
      b1.u = wf2[(nt * 2 + 1) * 64 + lane];
      f32x4 acc = {0.f, 0.f, 0.f, 0.f};
      acc = __builtin_amdgcn_mfma_f32_16x16x32_bf16(aL0.v, b0.v, acc, 0, 0, 0);
      acc = __builtin_amdgcn_mfma_f32_16x16x32_bf16(aL1.v, b1.v, acc, 0, 0, 0);
      acc = __builtin_amdgcn_mfma_f32_16x16x32_bf16(aH0.v, b0.v, acc, 0, 0, 0);
      acc = __builtin_amdgcn_mfma_f32_16x16x32_bf16(aH1.v, b1.v, acc, 0, 0, 0);
      int col = nt * 16 + l15;                 // channel c (0..127)
      float bias = (col < 64) ? bp1[col] : bh1[col - 64];
#pragma unroll
      for (int r = 0; r < 4; ++r) {
        int row = mt * 16 + quad * 4 + r;      // batch b (0..31)
        float v = acc[r] + bias;
        float g = 0.5f * v * (1.0f + erff(v * 0.70710678118654752f));
        if (col < 64) {                        // wave-uniform branch (nt<4)
          unsigned short hi = f2b(g);
          unsigned short lo = f2b(g - b2f(hi));
          int fi = ((mt * 2 + (col >> 5)) * 64 + ((col >> 3) & 3) * 16 + (row & 15)) * 8
                   + (col & 7);
          HHi[fi] = hi; HLo[fi] = lo;
        } else {
          Hv[row * 65 + (col - 64)] = g;
        }
      }
    }
  }
  __syncthreads();

  // ---- phase 3c: logits via MFMA (8 tiles, 1/wave) + value head ---------
  {
    const unsigned short* HHi = (const unsigned short*)Els;
    const unsigned short* HLo = (const unsigned short*)((char*)Els + 4096);
    const float* Hv = (const float*)((char*)Els + 8192);
    const int mt = w >> 2, nt = w & 3;
    union { uint4 u; bf16x8 v; } aH0, aH1, aL0, aL1, b0, b1;
    aH0.u = *(const uint4*)&HHi[((mt * 2 + 0) * 64 + lane) * 8];
    aH1.u = *(const uint4*)&HHi[((mt * 2 + 1) * 64 + lane) * 8];
    aL0.u = *(const uint4*)&HLo[((mt * 2 + 0) * 64 + lane) * 8];
    aL1.u = *(const uint4*)&HLo[((mt * 2 + 1) * 64 + lane) * 8];
    b0.u = wf3[(nt * 2 + 0) * 64 + lane];
    b1.u = wf3[(nt * 2 + 1) * 64 + lane];
    f32x4 acc = {0.f, 0.f, 0.f, 0.f};
    acc = __builtin_amdgcn_mfma_f32_16x16x32_bf16(aL0.v, b0.v, acc, 0, 0, 0);
    acc = __builtin_amdgcn_mfma_f32_16x16x32_bf16(aL1.v, b1.v, acc, 0, 0, 0);
    acc = __builtin_amdgcn_mfma_f32_16x16x32_bf16(aH0.v, b0.v, acc, 0, 0, 0);
    acc = __builtin_amdgcn_mfma_f32_16x16x32_bf16(aH1.v, b1.v, acc, 0, 0, 0);
    int col = nt * 16 + l15;                   // output o (0..63, valid <50)
    if (col < 50) {
      float bias = bp2[col];
#pragma unroll
      for (int r = 0; r < 4; ++r) {
        int row = mt * 16 + quad * 4 + r;
        long gb = (long)blockIdx.x * 32 + row;
        out[gb * 50 + col] = acc[r] + bias;
      }
    }
    if (t < 32) {                              // value head: hv @ Wh2 + bh2
      float s = bh2[0];
#pragma unroll
      for (int j = 0; j < 64; ++j)
        s = __builtin_fmaf(Hv[t * 65 + j], Wh2[j], s);
      out[(long)B * 50 + (long)blockIdx.x * 32 + t] = s;
    }
  }
}

// --------------------------------------------------------------- launch ----
extern "C" void kernel_launch(void* const* d_in, const int* in_sizes, int n_in,
                              void* d_out, int out_size, void* d_ws, size_t ws_size,
                              hipStream_t stream) {
  const float* x   = (const float*)d_in[0];
  const float* Wk  = (const float*)d_in[1];
  const float* bk  = (const float*)d_in[2];
  const float* Wq  = (const float*)d_in[3];
  const float* bq  = (const float*)d_in[4];
  const float* Wv  = (const float*)d_in[5];
  const float* bv  = (const float*)d_in[6];
  const float* Wr  = (const float*)d_in[7];
  const float* br  = (const float*)d_in[8];
  const float* Wp1 = (const float*)d_in[9];
  const float* bp1 = (const float*)d_in[10];
  const float* Wp2 = (const float*)d_in[11];
  const float* bp2 = (const float*)d_in[12];
  const float* Wh1 = (const float*)d_in[13];
  const float* bh1 = (const float*)d_in[14];
  const float* Wh2 = (const float*)d_in[15];
  const float* bh2 = (const float*)d_in[16];

  int B = in_sizes[0] / 320;  // 131072

  setup_kernel<<<1, 256, 0, stream>>>(Wk, bk, Wq, bq, Wv, bv, Wr, br,
                                      Wp1, Wh1, Wp2, (char*)d_ws);
  policy_kernel<<<B / 32, 512, 0, stream>>>(x, (const char*)d_ws,
                                            bp1, bp2, bh1, bh2, Wh2,
                                            (float*)d_out, B);
}

// Round 2
// 381.674 us; speedup vs baseline: 1.3531x; 1.1620x over previous
//
#include <hip/hip_runtime.h>
#include <stdint.h>

// LightMetaPolicy fused kernel, round 7:
//  - __launch_bounds__(512,2): round-6's (512,4) was interpreted as CUDA
//    min-BLOCKS/CU semantics -> 32 waves/CU target -> 64-VGPR cap -> scratch
//    spill (+125 MB HBM writes, VGPR_Count=64). (512,2) = 16 waves/CU ->
//    128-VGPR budget (round 5 proved phase-1 fits in 128). LDS already caps
//    at 2 blocks/CU, so occupancy is unchanged.
//  - Phase 2 (attention scores) spread over all 512 threads (was 160): 800
//    score dots via grid-stride into asw, then a light 160-thread softmax.
//  - wk[b][k] (attn column sums) and inv[b] hoisted out of phase 3a into a
//    one-shot 160-thread pass (was 25 adds per (b,d) element).
//
// Folds: R = x@(Wr@Wq)^T + (Wr@bq+br); pooled via column-sum of masked A.
// E LDS per agent-row: cols [0:32)=Q, [32:64)=K, [64:96)=R, [96:160)=V
//
// MFMA 16x16x32 bf16 layouts (m89-verified):
//   A: lane holds A[m=lane&15][k=quad*8+j], j=0..7  (quad=lane>>4)
//   B: lane holds B[k=quad*8+j][n=lane&15]
//   C: lane reg r holds C[row=quad*4+r][col=lane&15]

typedef __attribute__((ext_vector_type(8))) short bf16x8;
typedef __attribute__((ext_vector_type(4))) float f32x4;

#define ESTR 162   // E stride (shorts): 81 dwords, odd -> conflict-free rows

#define WF1_OFF 0      // phase-1 B-frags: 20 frags * 64 lanes * 16B = 20480
#define BC_OFF  20480  // bcat f32[160] = 640
#define WF2_OFF 21120  // phase-3b B-frags: 16 frags * 1024B = 16384
#define WF3_OFF 37504  // phase-3c B-frags:  8 frags * 1024B = 8192
// ws total: 45696 B

__device__ __forceinline__ float b2f_lo(unsigned int pk) {
  union { unsigned int i; float f; } v; v.i = pk << 16; return v.f;
}
__device__ __forceinline__ float b2f_hi(unsigned int pk) {
  union { unsigned int i; float f; } v; v.i = pk & 0xffff0000u; return v.f;
}
__device__ __forceinline__ float b2f(unsigned short u) {
  union { unsigned int i; float f; } v; v.i = ((unsigned int)u) << 16; return v.f;
}
__device__ __forceinline__ unsigned short f2b(float f) {
  union { float f; unsigned int i; } v; v.f = f;
  unsigned int u = v.i;
  return (unsigned short)((u + 0x7fffu + ((u >> 16) & 1u)) >> 16);  // RNE
}

// ---------------------------------------------------------------- setup ----
__global__ void setup_kernel(const float* __restrict__ Wk,
                             const float* __restrict__ bk,
                             const float* __restrict__ Wq,
                             const float* __restrict__ bq,
                             const float* __restrict__ Wv,
                             const float* __restrict__ bv,
                             const float* __restrict__ Wr,
                             const float* __restrict__ br,
                             const float* __restrict__ Wp1,
                             const float* __restrict__ Wh1,
                             const float* __restrict__ Wp2,
                             char* __restrict__ ws) {
  __shared__ float Wrp[32 * 64];  // Wr' = Wr @ Wq
  const int t = threadIdx.x;
  for (int i = t; i < 32 * 64; i += 256) {
    int rr = i >> 6, d = i & 63;
    float acc = 0.f;
    for (int m = 0; m < 32; ++m) acc += Wr[rr * 32 + m] * Wq[m * 64 + d];
    Wrp[i] = acc;
  }
  __syncthreads();

  unsigned short* wf1 = (unsigned short*)(ws + WF1_OFF);
  float* bc = (float*)(ws + BC_OFF);
  unsigned short* wf2 = (unsigned short*)(ws + WF2_OFF);
  unsigned short* wf3 = (unsigned short*)(ws + WF3_OFF);

  // phase-1 B-frags: fs = nt*2+s (nt 0..9, s 0..1)
  for (int i = t; i < 20 * 64 * 8; i += 256) {
    int j = i & 7, l = (i >> 3) & 63, fs = i >> 9;
    int nt = fs >> 1, s = fs & 1;
    int r = nt * 16 + (l & 15);            // output channel (Wcat row)
    int k = s * 32 + ((l >> 4) & 3) * 8 + j;
    float w;
    if (r < 32)      w = Wq[r * 64 + k];
    else if (r < 64) w = Wk[(r - 32) * 64 + k];
    else if (r < 96) w = Wrp[(r - 64) * 64 + k];
    else             w = Wv[(r - 96) * 64 + k];
    wf1[i] = f2b(w);
  }
  if (t < 160) {
    int r = t;
    float v;
    if (r < 32)      v = bq[r];
    else if (r < 64) v = bk[r - 32];
    else if (r < 96) {
      int rr = r - 64;
      float acc = br[rr];
      for (int m = 0; m < 32; ++m) acc += Wr[rr * 32 + m] * bq[m];
      v = acc;
    } else            v = bv[r - 96];
    bc[r] = v;
  }
  // phase-3b B-frags (Wmlp = [Wp1;Wh1], 128x64): fs = nt*2+s, nt 0..7
  for (int i = t; i < 16 * 64 * 8; i += 256) {
    int j = i & 7, l = (i >> 3) & 63, fs = i >> 9;
    int nt = fs >> 1, s = fs & 1;
    int n = nt * 16 + (l & 15);
    int k = s * 32 + ((l >> 4) & 3) * 8 + j;
    float wv = (n < 64) ? Wp1[n * 64 + k] : Wh1[(n - 64) * 64 + k];
    wf2[i] = f2b(wv);
  }
  // phase-3c B-frags (Wp2, 50x64 zero-padded to 64): fs = nt*2+s, nt 0..3
  for (int i = t; i < 8 * 64 * 8; i += 256) {
    int j = i & 7, l = (i >> 3) & 63, fs = i >> 9;
    int nt = fs >> 1, s = fs & 1;
    int n = nt * 16 + (l & 15);
    int k = s * 32 + ((l >> 4) & 3) * 8 + j;
    float wv = (n < 50) ? Wp2[n * 64 + k] : 0.f;
    wf3[i] = f2b(wv);
  }
}

// ----------------------------------------------------------------- main ----
__global__ __launch_bounds__(512, 2)
void policy_kernel(const float* __restrict__ x,
                   const char* __restrict__ ws,
                   const float* __restrict__ bp1,
                   const float* __restrict__ bp2,
                   const float* __restrict__ bh1,
                   const float* __restrict__ bh2,
                   const float* __restrict__ Wh2,
                   float* __restrict__ out, int B) {
  // 32 batches/block = 160 agent-rows. 8 waves.
  __shared__ __align__(16) unsigned short Els[160 * ESTR];  // 51,840 B
  __shared__ float maskLs[160];                             // 640 B
  __shared__ float asw[32 * 25];                            // 3,200 B
  __shared__ float wkLs[160];                               // 640 B
  __shared__ float invLs[32];                               // 128 B
  // pooled in MFMA A-frag layout, split bf16: frag f = (mt*2+s), f 0..3
  __shared__ __align__(16) unsigned short pHi[4 * 64 * 8];  // 4,096 B
  __shared__ __align__(16) unsigned short pLo[4 * 64 * 8];  // 4,096 B
  // total 64,640 B -> 2 blocks/CU (16 waves)

  const int t = threadIdx.x;
  const int w = t >> 6, lane = t & 63;
  const int l15 = lane & 15, quad = lane >> 4;

  const uint4* wf1 = (const uint4*)(ws + WF1_OFF);
  const float* bc = (const float*)(ws + BC_OFF);
  const uint4* wf2 = (const uint4*)(ws + WF2_OFF);
  const uint4* wf3 = (const uint4*)(ws + WF3_OFF);

  // ---- phase 0: agent mask (also pre-warms the x tile in L1/L2) ---------
  if (t < 160) {
    long row = (long)blockIdx.x * 160 + t;
    const float4* xp = (const float4*)(x + row * 64);
    float ms = 0.f;
#pragma unroll
    for (int i = 0; i < 16; ++i) {
      float4 v = xp[i];
      ms += fabsf(v.x) + fabsf(v.y) + fabsf(v.z) + fabsf(v.w);
    }
    maskLs[t] = (ms > 0.01f) ? 1.f : 0.f;
  }

  // ---- phase 1: E = x @ Wcat^T + bcat via MFMA, split-bf16 x ------------
  // 100 tiles (m 0..9, n 0..9) over 8 waves, m-contiguous ranges so the
  // split-bf16 x conversion amortizes (2-3 m-values per wave).
  {
    union { uint4 u; bf16x8 v; } ah0, ah1, al0, al1;  // hi/lo x k-halves
    int mcur = -1;
    const int start = (w < 4) ? w * 13 : 52 + (w - 4) * 12;
    const int cnt = (w < 4) ? 13 : 12;
    for (int ti = 0; ti < cnt; ++ti) {
      int tt = start + ti;
      int m = tt / 10, n = tt - m * 10;
      if (m != mcur) {
        mcur = m;
        long row = (long)blockIdx.x * 160 + m * 16 + l15;
        const float* xr = x + row * 64 + quad * 8;
        float xv[16];
        *(float4*)(xv + 0)  = *(const float4*)(xr);
        *(float4*)(xv + 4)  = *(const float4*)(xr + 4);
        *(float4*)(xv + 8)  = *(const float4*)(xr + 32);
        *(float4*)(xv + 12) = *(const float4*)(xr + 36);
        unsigned int hw[8], lw[8];
#pragma unroll
        for (int i = 0; i < 8; ++i) {
          unsigned short h0 = f2b(xv[2 * i]);
          unsigned short h1 = f2b(xv[2 * i + 1]);
          float r0 = xv[2 * i]     - b2f(h0);
          float r1 = xv[2 * i + 1] - b2f(h1);
          hw[i] = (unsigned int)h0 | ((unsigned int)h1 << 16);
          lw[i] = (unsigned int)f2b(r0) | ((unsigned int)f2b(r1) << 16);
        }
        ah0.u = make_uint4(hw[0], hw[1], hw[2], hw[3]);
        ah1.u = make_uint4(hw[4], hw[5], hw[6], hw[7]);
        al0.u = make_uint4(lw[0], lw[1], lw[2], lw[3]);
        al1.u = make_uint4(lw[4], lw[5], lw[6], lw[7]);
      }
      union { uint4 u; bf16x8 v; } b0, b1;
      b0.u = wf1[(n * 2 + 0) * 64 + lane];
      b1.u = wf1[(n * 2 + 1) * 64 + lane];
      f32x4 acc = {0.f, 0.f, 0.f, 0.f};
      acc = __builtin_amdgcn_mfma_f32_16x16x32_bf16(al0.v, b0.v, acc, 0, 0, 0);
      acc = __builtin_amdgcn_mfma_f32_16x16x32_bf16(al1.v, b1.v, acc, 0, 0, 0);
      acc = __builtin_amdgcn_mfma_f32_16x16x32_bf16(ah0.v, b0.v, acc, 0, 0, 0);
      acc = __builtin_amdgcn_mfma_f32_16x16x32_bf16(ah1.v, b1.v, acc, 0, 0, 0);
      float bias = bc[n * 16 + l15];
      int r0 = m * 16 + quad * 4;
      int col = n * 16 + l15;
#pragma unroll
      for (int r = 0; r < 4; ++r)
        Els[(r0 + r) * ESTR + col] = f2b(acc[r] + bias);
    }
  }
  __syncthreads();

  // ---- phase 2a: S[b][q][k] = scale*(Q·K + R·R), all 512 threads --------
  for (int i = t; i < 800; i += 512) {
    int b = i / 25, rem = i - 25 * b;
    int q = rem / 5, k = rem - 5 * q;
    const unsigned short* rq = &Els[(5 * b + q) * ESTR];
    const unsigned short* rk = &Els[(5 * b + k) * ESTR];
    float ax = 0.f, ay = 0.f;
#pragma unroll
    for (int j = 0; j < 16; ++j) {        // Q[q] . K[k]
      unsigned int pq = *(const unsigned int*)&rq[2 * j];
      unsigned int pk = *(const unsigned int*)&rk[32 + 2 * j];
      ax = __builtin_fmaf(b2f_lo(pq), b2f_lo(pk), ax);
      ay = __builtin_fmaf(b2f_hi(pq), b2f_hi(pk), ay);
    }
#pragma unroll
    for (int j = 0; j < 16; ++j) {        // R[q] . R[k]
      unsigned int pq = *(const unsigned int*)&rq[64 + 2 * j];
      unsigned int pk = *(const unsigned int*)&rk[64 + 2 * j];
      ax = __builtin_fmaf(b2f_lo(pq), b2f_lo(pk), ax);
      ay = __builtin_fmaf(b2f_hi(pq), b2f_hi(pk), ay);
    }
    asw[i] = (ax + ay) * 0.17677669529663689f;
  }
  __syncthreads();

  // ---- phase 2b: softmax over k per (b,q), apply mask/denominator -------
  if (t < 160) {
    const int base = (t / 5) * 25 + (t - 5 * (t / 5)) * 5;
    float sc[5];
#pragma unroll
    for (int k = 0; k < 5; ++k) sc[k] = asw[base + k];
    float mx = sc[0];
#pragma unroll
    for (int k = 1; k < 5; ++k) mx = fmaxf(mx, sc[k]);
    float p[5], ps = 0.f;
#pragma unroll
    for (int k = 0; k < 5; ++k) { p[k] = __expf(sc[k] - mx); ps += p[k]; }
    float mscale = maskLs[t] / ps;
#pragma unroll
    for (int k = 0; k < 5; ++k) asw[base + k] = p[k] * mscale;
  }
  __syncthreads();

  // ---- phase 2c: wk[b][k] = sum_q asw, inv[b] = 1/(mask sum) ------------
  if (t < 160) {
    const int b = t / 5, k = t - 5 * b;
    const float* ab = &asw[b * 25];
    wkLs[t] = ab[k] + ab[5 + k] + ab[10 + k] + ab[15 + k] + ab[20 + k];
  }
  if (t < 32) {
    float msum = maskLs[t * 5] + maskLs[t * 5 + 1] + maskLs[t * 5 + 2] +
                 maskLs[t * 5 + 3] + maskLs[t * 5 + 4];
    invLs[t] = 1.0f / (msum + 1e-8f);
  }
  __syncthreads();

  // ---- phase 3a: pooled = inv * sum_k wk[k]*V[k][:], write as A-frags ---
  for (int i = t; i < 32 * 64; i += 512) {
    int b = i >> 6, d = i & 63;
    const float* wk = &wkLs[b * 5];
    float acc = 0.f;
#pragma unroll
    for (int k = 0; k < 5; ++k)
      acc = __builtin_fmaf(wk[k], b2f(Els[(5 * b + k) * ESTR + 96 + d]), acc);
    float pv = acc * invLs[b];
    unsigned short hi = f2b(pv);
    unsigned short lo = f2b(pv - b2f(hi));
    // A-frag position: frag (b>>4)*2 + (d>>5), lane ((d>>3)&3)*16 + (b&15),
    // element d&7  (A: lane holds A[m=lane&15][k=quad*8+j])
    int fi = (((b >> 4) * 2 + (d >> 5)) * 64 + ((d >> 3) & 3) * 16 + (b & 15)) * 8
             + (d & 7);
    pHi[fi] = hi; pLo[fi] = lo;
  }
  __syncthreads();

  // ---- phase 3b: H = gelu(pooled @ Wmlp^T + bias) via MFMA --------------
  // 16 tiles (mt 0..1, nt 0..7); wave w: mt=w>>2, nt=(w&3)*2+{0,1}.
  // H cols <64 written as split-bf16 A-frags (for 3c MFMA); cols >=64 as
  // f32 rows (value head). All land in the now-dead Els region.
  {
    unsigned short* HHi = (unsigned short*)Els;                    // 4,096 B
    unsigned short* HLo = (unsigned short*)((char*)Els + 4096);    // 4,096 B
    float* Hv = (float*)((char*)Els + 8192);                       // [32][65] f32
    const int mt = w >> 2;
    union { uint4 u; bf16x8 v; } aH0, aH1, aL0, aL1;
    aH0.u = *(const uint4*)&pHi[((mt * 2 + 0) * 64 + lane) * 8];
    aH1.u = *(const uint4*)&pHi[((mt * 2 + 1) * 64 + lane) * 8];
    aL0.u = *(const uint4*)&pLo[((mt * 2 + 0) * 64 + lane) * 8];
    aL1.u = *(const uint4*)&pLo[((mt * 2 + 1) * 64 + lane) * 8];
#pragma unroll
    for (int tI = 0; tI < 2; ++tI) {
      int nt = (w & 3) * 2 + tI;
      union { uint4 u; bf16x8 v; } b0, b1;
      b0.u = wf2[(nt * 2 + 0) * 64 + lane];
      b1.u = wf2[(nt * 2 + 1) * 64 + lane];
      f32x4 acc = {0.f, 0.f, 0.f, 0.f};
      acc = __builtin_amdgcn_mfma_f32_16x16x32_bf16(aL0.v, b0.v, acc, 0, 0, 0);
      acc = __builtin_amdgcn_mfma_f32_16x16x32_bf16(aL1.v, b1.v, acc, 0, 0, 0);
      acc = __builtin_amdgcn_mfma_f32_16x16x32_bf16(aH0.v, b0.v, acc, 0, 0, 0);
      acc = __builtin_amdgcn_mfma_f32_16x16x32_bf16(aH1.v, b1.v, acc, 0, 0, 0);
      int col = nt * 16 + l15;                 // channel c (0..127)
      float bias = (col < 64) ? bp1[col] : bh1[col - 64];
#pragma unroll
      for (int r = 0; r < 4; ++r) {
        int row = mt * 16 + quad * 4 + r;      // batch b (0..31)
        float v = acc[r] + bias;
        float g = 0.5f * v * (1.0f + erff(v * 0.70710678118654752f));
        if (col < 64) {                        // wave-uniform branch (nt<4)
          unsigned short hi = f2b(g);
          unsigned short lo = f2b(g - b2f(hi));
          int fi = ((mt * 2 + (col >> 5)) * 64 + ((col >> 3) & 3) * 16 + (row & 15)) * 8
                   + (col & 7);
          HHi[fi] = hi; HLo[fi] = lo;
        } else {
          Hv[row * 65 + (col - 64)] = g;
        }
      }
    }
  }
  __syncthreads();

  // ---- phase 3c: logits via MFMA (8 tiles, 1/wave) + value head ---------
  {
    const unsigned short* HHi = (const unsigned short*)Els;
    const unsigned short* HLo = (const unsigned short*)((char*)Els + 4096);
    const float* Hv = (const float*)((char*)Els + 8192);
    const int mt = w >> 2, nt = w & 3;
    union { uint4 u; bf16x8 v; } aH0, aH1, aL0, aL1, b0, b1;
    aH0.u = *(const uint4*)&HHi[((mt * 2 + 0) * 64 + lane) * 8];
    aH1.u = *(const uint4*)&HHi[((mt * 2 + 1) * 64 + lane) * 8];
    aL0.u = *(const uint4*)&HLo[((mt * 2 + 0) * 64 + lane) * 8];
    aL1.u = *(const uint4*)&HLo[((mt * 2 + 1) * 64 + lane) * 8];
    b0.u = wf3[(nt * 2 + 0) * 64 + lane];
    b1.u = wf3[(nt * 2 + 1) * 64 + lane];
    f32x4 acc = {0.f, 0.f, 0.f, 0.f};
    acc = __builtin_amdgcn_mfma_f32_16x16x32_bf16(aL0.v, b0.v, acc, 0, 0, 0);
    acc = __builtin_amdgcn_mfma_f32_16x16x32_bf16(aL1.v, b1.v, acc, 0, 0, 0);
    acc = __builtin_amdgcn_mfma_f32_16x16x32_bf16(aH0.v, b0.v, acc, 0, 0, 0);
    acc = __builtin_amdgcn_mfma_f32_16x16x32_bf16(aH1.v, b1.v, acc, 0, 0, 0);
    int col = nt * 16 + l15;                   // output o (0..63, valid <50)
    if (col < 50) {
      float bias = bp2[col];
#pragma unroll
      for (int r = 0; r < 4; ++r) {
        int row = mt * 16 + quad * 4 + r;
        long gb = (long)blockIdx.x * 32 + row;
        out[gb * 50 + col] = acc[r] + bias;
      }
    }
    if (t < 32) {                              // value head: hv @ Wh2 + bh2
      float s = bh2[0];
#pragma unroll
      for (int j = 0; j < 64; ++j)
        s = __builtin_fmaf(Hv[t * 65 + j], Wh2[j], s);
      out[(long)B * 50 + (long)blockIdx.x * 32 + t] = s;
    }
  }
}

// --------------------------------------------------------------- launch ----
extern "C" void kernel_launch(void* const* d_in, const int* in_sizes, int n_in,
                              void* d_out, int out_size, void* d_ws, size_t ws_size,
                              hipStream_t stream) {
  const float* x   = (const float*)d_in[0];
  const float* Wk  = (const float*)d_in[1];
  const float* bk  = (const float*)d_in[2];
  const float* Wq  = (const float*)d_in[3];
  const float* bq  = (const float*)d_in[4];
  const float* Wv  = (const float*)d_in[5];
  const float* bv  = (const float*)d_in[6];
  const float* Wr  = (const float*)d_in[7];
  const float* br  = (const float*)d_in[8];
  const float* Wp1 = (const float*)d_in[9];
  const float* bp1 = (const float*)d_in[10];
  const float* Wp2 = (const float*)d_in[11];
  const float* bp2 = (const float*)d_in[12];
  const float* Wh1 = (const float*)d_in[13];
  const float* bh1 = (const float*)d_in[14];
  const float* Wh2 = (const float*)d_in[15];
  const float* bh2 = (const float*)d_in[16];

  int B = in_sizes[0] / 320;  // 131072

  setup_kernel<<<1, 256, 0, stream>>>(Wk, bk, Wq, bq, Wv, bv, Wr, br,
                                      Wp1, Wh1, Wp2, (char*)d_ws);
  policy_kernel<<<B / 32, 512, 0, stream>>>(x, (const char*)d_ws,
                                            bp1, bp2, bh1, bh2, Wh2,
                                            (float*)d_out, B);
}

// Round 4
// 348.012 us; speedup vs baseline: 1.4840x; 1.0967x over previous
//
#include <hip/hip_runtime.h>
#include <stdint.h>

// LightMetaPolicy fused kernel, round 8 (resubmit — round-3 bench hit a GPU
// acquisition timeout; no measurement was taken):
//  - bf16-split moved from x to W (Whi+Wlo precomputed in setup; error budget
//    dominated by bf16 E-storage either way). x converted to single bf16 ONCE
//    per m-tile in phase 1a, staged as A-frags in LDS (aliased scratch).
//  - Phase 1b n-major per wave: B-frags (4/n) loaded once per n from ws.
//  - Agent-mask fused into phase 1a (cross-quad shfl reduce) - x read once.
//  - Phase 2 attention scores via MFMA: 15-row windows, A-pattern load used
//    as both A and B operand gives Eqr @ Ekr^T directly (R-frag reused).
//    ESTR=168 (16B-aligned rows for ds_read_b128; 84 dwords = 2-way banks).
//  - Softmax + column-sum fused (wk computed from raw scores; 1 barrier less).
//
// E LDS per agent-row: cols [0:32)=Q, [32:64)=K, [64:96)=R, [96:160)=V
//
// MFMA 16x16x32 bf16 layouts (m89-verified):
//   A: lane holds A[m=lane&15][k=quad*8+j], j=0..7  (quad=lane>>4)
//   B: lane holds B[k=quad*8+j][n=lane&15]
//   C: lane reg r holds C[row=quad*4+r][col=lane&15]
// Passing an A-pattern register (X[l15][quad*8+j]) as the B operand yields
// B[k][n] = X[n][k], i.e. C = A @ X^T.

typedef __attribute__((ext_vector_type(8))) short bf16x8;
typedef __attribute__((ext_vector_type(4))) float f32x4;

#define ESTR 168   // shorts; 336B rows: 16B-aligned, 84 dwords -> 2-way banks

#define WF1_OFF 0      // phase-1 B-frags: 40 frags (10n x {hi,lo} x 2k) = 40960
#define BC_OFF  40960  // bcat f32[160] = 640
#define WF2_OFF 41600  // phase-3b B-frags: 16 frags = 16384
#define WF3_OFF 57984  // phase-3c B-frags:  8 frags = 8192
// ws total: 66176 B

__device__ __forceinline__ float b2f_lo(unsigned int pk) {
  union { unsigned int i; float f; } v; v.i = pk << 16; return v.f;
}
__device__ __forceinline__ float b2f_hi(unsigned int pk) {
  union { unsigned int i; float f; } v; v.i = pk & 0xffff0000u; return v.f;
}
__device__ __forceinline__ float b2f(unsigned short u) {
  union { unsigned int i; float f; } v; v.i = ((unsigned int)u) << 16; return v.f;
}
__device__ __forceinline__ unsigned short f2b(float f) {
  union { float f; unsigned int i; } v; v.f = f;
  unsigned int u = v.i;
  return (unsigned short)((u + 0x7fffu + ((u >> 16) & 1u)) >> 16);  // RNE
}

// ---------------------------------------------------------------- setup ----
__global__ void setup_kernel(const float* __restrict__ Wk,
                             const float* __restrict__ bk,
                             const float* __restrict__ Wq,
                             const float* __restrict__ bq,
                             const float* __restrict__ Wv,
                             const float* __restrict__ bv,
                             const float* __restrict__ Wr,
                             const float* __restrict__ br,
                             const float* __restrict__ Wp1,
                             const float* __restrict__ Wh1,
                             const float* __restrict__ Wp2,
                             char* __restrict__ ws) {
  __shared__ float Wrp[32 * 64];  // Wr' = Wr @ Wq
  const int t = threadIdx.x;
  for (int i = t; i < 32 * 64; i += 256) {
    int rr = i >> 6, d = i & 63;
    float acc = 0.f;
    for (int m = 0; m < 32; ++m) acc += Wr[rr * 32 + m] * Wq[m * 64 + d];
    Wrp[i] = acc;
  }
  __syncthreads();

  unsigned short* wf1 = (unsigned short*)(ws + WF1_OFF);
  float* bc = (float*)(ws + BC_OFF);
  unsigned short* wf2 = (unsigned short*)(ws + WF2_OFF);
  unsigned short* wf3 = (unsigned short*)(ws + WF3_OFF);

  // phase-1 B-frags, SPLIT hi/lo: frag f = n*4 + h*2 + s
  //   (n 0..9 = 16-col tile, h 0=hi 1=lo, s = k-half)
  for (int i = t; i < 40 * 64 * 8; i += 256) {
    int j = i & 7, l = (i >> 3) & 63, f = i >> 9;
    int n = f >> 2, h = (f >> 1) & 1, s = f & 1;
    int r = n * 16 + (l & 15);             // output channel (Wcat row)
    int k = s * 32 + ((l >> 4) & 3) * 8 + j;
    float w;
    if (r < 32)      w = Wq[r * 64 + k];
    else if (r < 64) w = Wk[(r - 32) * 64 + k];
    else if (r < 96) w = Wrp[(r - 64) * 64 + k];
    else             w = Wv[(r - 96) * 64 + k];
    unsigned short hi = f2b(w);
    wf1[i] = h ? f2b(w - b2f(hi)) : hi;
  }
  if (t < 160) {
    int r = t;
    float v;
    if (r < 32)      v = bq[r];
    else if (r < 64) v = bk[r - 32];
    else if (r < 96) {
      int rr = r - 64;
      float acc = br[rr];
      for (int m = 0; m < 32; ++m) acc += Wr[rr * 32 + m] * bq[m];
      v = acc;
    } else            v = bv[r - 96];
    bc[r] = v;
  }
  // phase-3b B-frags (Wmlp = [Wp1;Wh1], 128x64): fs = nt*2+s, nt 0..7
  for (int i = t; i < 16 * 64 * 8; i += 256) {
    int j = i & 7, l = (i >> 3) & 63, fs = i >> 9;
    int nt = fs >> 1, s = fs & 1;
    int n = nt * 16 + (l & 15);
    int k = s * 32 + ((l >> 4) & 3) * 8 + j;
    float wv = (n < 64) ? Wp1[n * 64 + k] : Wh1[(n - 64) * 64 + k];
    wf2[i] = f2b(wv);
  }
  // phase-3c B-frags (Wp2, 50x64 zero-padded to 64): fs = nt*2+s, nt 0..3
  for (int i = t; i < 8 * 64 * 8; i += 256) {
    int j = i & 7, l = (i >> 3) & 63, fs = i >> 9;
    int nt = fs >> 1, s = fs & 1;
    int n = nt * 16 + (l & 15);
    int k = s * 32 + ((l >> 4) & 3) * 8 + j;
    float wv = (n < 50) ? Wp2[n * 64 + k] : 0.f;
    wf3[i] = f2b(wv);
  }
}

// ----------------------------------------------------------------- main ----
__global__ __launch_bounds__(512, 2)
void policy_kernel(const float* __restrict__ x,
                   const char* __restrict__ ws,
                   const float* __restrict__ bp1,
                   const float* __restrict__ bp2,
                   const float* __restrict__ bh1,
                   const float* __restrict__ bh2,
                   const float* __restrict__ Wh2,
                   float* __restrict__ out, int B) {
  // 32 batches/block = 160 agent-rows. 8 waves.
  // LDS pool (74,880 B -> 2 blocks/CU):
  //   [0      .. 53,760)  Els  160 x ESTR bf16   (phase 3b reuses as H)
  //   [53,760 .. 54,400)  maskLs f32[160]
  //   [54,400 .. 74,880)  union:
  //     phase 1 : xfrag  20 frags (10m x 2k) x 1KB = 20,480
  //     phase 2+: asw f32[800]=3,200 | wkLs f32[160]=640 | invLs f32[32]=128
  //               pHi 4,096 @ +3,968 | pLo 4,096
  __shared__ __align__(16) char shpool[74880];
  unsigned short* Els = (unsigned short*)shpool;
  float* maskLs = (float*)(shpool + 53760);
  unsigned short* xfrag = (unsigned short*)(shpool + 54400);
  float* asw  = (float*)(shpool + 54400);
  float* wkLs = (float*)(shpool + 57600);
  float* invLs = (float*)(shpool + 58240);
  unsigned short* pHi = (unsigned short*)(shpool + 58368);
  unsigned short* pLo = (unsigned short*)(shpool + 62464);

  const int t = threadIdx.x;
  const int w = t >> 6, lane = t & 63;
  const int l15 = lane & 15, quad = lane >> 4;

  const uint4* wf1 = (const uint4*)(ws + WF1_OFF);
  const float* bc = (const float*)(ws + BC_OFF);
  const uint4* wf2 = (const uint4*)(ws + WF2_OFF);
  const uint4* wf3 = (const uint4*)(ws + WF3_OFF);

  // ---- phase 1a: convert x -> bf16 A-frags in LDS; fused agent mask -----
  // Lane layout per m-tile: row = m*16+l15, cols [quad*8,quad*8+8) and +32.
  for (int m = w; m < 10; m += 8) {
    long row = (long)blockIdx.x * 160 + m * 16 + l15;
    const float* xr = x + row * 64 + quad * 8;
    float xv[16];
    *(float4*)(xv + 0)  = *(const float4*)(xr);
    *(float4*)(xv + 4)  = *(const float4*)(xr + 4);
    *(float4*)(xv + 8)  = *(const float4*)(xr + 32);
    *(float4*)(xv + 12) = *(const float4*)(xr + 36);
    float ms = 0.f;
#pragma unroll
    for (int i = 0; i < 16; ++i) ms += fabsf(xv[i]);
    ms += __shfl_xor(ms, 16, 64);    // reduce across the 4 quads
    ms += __shfl_xor(ms, 32, 64);
    if (quad == 0) maskLs[m * 16 + l15] = (ms > 0.01f) ? 1.f : 0.f;
    unsigned int pk[8];
#pragma unroll
    for (int i = 0; i < 8; ++i)
      pk[i] = (unsigned int)f2b(xv[2 * i]) |
              ((unsigned int)f2b(xv[2 * i + 1]) << 16);
    *(uint4*)&xfrag[((m * 2 + 0) * 64 + lane) * 8] =
        make_uint4(pk[0], pk[1], pk[2], pk[3]);
    *(uint4*)&xfrag[((m * 2 + 1) * 64 + lane) * 8] =
        make_uint4(pk[4], pk[5], pk[6], pk[7]);
  }
  __syncthreads();

  // ---- phase 1b: E = xb @ (Whi+Wlo)^T + bcat, n-major tiles -------------
  {
    union { uint4 u; bf16x8 v; } bh0, bh1, bl0, bl1, a0, a1;
    int ncur = -1;
    float bias = 0.f;
    const int start = (w < 4) ? w * 13 : 52 + (w - 4) * 12;
    const int cnt = (w < 4) ? 13 : 12;
    for (int ti = 0; ti < cnt; ++ti) {
      int tt = start + ti;
      int n = tt / 10, m = tt - n * 10;
      if (n != ncur) {
        ncur = n;
        bh0.u = wf1[(n * 4 + 0) * 64 + lane];
        bh1.u = wf1[(n * 4 + 1) * 64 + lane];
        bl0.u = wf1[(n * 4 + 2) * 64 + lane];
        bl1.u = wf1[(n * 4 + 3) * 64 + lane];
        bias = bc[n * 16 + l15];
      }
      a0.u = *(const uint4*)&xfrag[((m * 2 + 0) * 64 + lane) * 8];
      a1.u = *(const uint4*)&xfrag[((m * 2 + 1) * 64 + lane) * 8];
      f32x4 acc = {0.f, 0.f, 0.f, 0.f};
      acc = __builtin_amdgcn_mfma_f32_16x16x32_bf16(a0.v, bh0.v, acc, 0, 0, 0);
      acc = __builtin_amdgcn_mfma_f32_16x16x32_bf16(a1.v, bh1.v, acc, 0, 0, 0);
      acc = __builtin_amdgcn_mfma_f32_16x16x32_bf16(a0.v, bl0.v, acc, 0, 0, 0);
      acc = __builtin_amdgcn_mfma_f32_16x16x32_bf16(a1.v, bl1.v, acc, 0, 0, 0);
      int r0 = m * 16 + quad * 4;
      int col = n * 16 + l15;
#pragma unroll
      for (int r = 0; r < 4; ++r)
        Els[(r0 + r) * ESTR + col] = f2b(acc[r] + bias);
    }
  }
  __syncthreads();

  // ---- phase 2: S = scale*(Q·K^T + R·R^T) via MFMA, 15-row windows ------
  // Tile ti covers agent rows [15ti, 15ti+16): batches 3ti..3ti+2 complete.
  // Off-diagonal / out-of-range C entries discarded (provably inert).
  for (int ti = w; ti < 11; ti += 8) {
    const unsigned short* ra = &Els[(ti * 15 + l15) * ESTR];
    union { uint4 u; bf16x8 v; } a0, a1, b0;
    a0.u = *(const uint4*)&ra[quad * 8];        // Q cols [0,32)
    b0.u = *(const uint4*)&ra[32 + quad * 8];   // K cols [32,64)
    a1.u = *(const uint4*)&ra[64 + quad * 8];   // R cols [64,96)
    f32x4 acc = {0.f, 0.f, 0.f, 0.f};
    acc = __builtin_amdgcn_mfma_f32_16x16x32_bf16(a0.v, b0.v, acc, 0, 0, 0);
    acc = __builtin_amdgcn_mfma_f32_16x16x32_bf16(a1.v, a1.v, acc, 0, 0, 0);
#pragma unroll
    for (int r = 0; r < 4; ++r) {
      int arq = ti * 15 + quad * 4 + r;   // query agent-row
      int ark = ti * 15 + l15;            // key agent-row
      int bq = arq / 5, qq = arq - 5 * bq;
      int bk2 = ark / 5, kk = ark - 5 * bk2;
      if (bq == bk2 && bq < 32)
        asw[bq * 25 + qq * 5 + kk] = acc[r] * 0.17677669529663689f;
    }
  }
  __syncthreads();

  // ---- phase 2bc: wk[b][k] = sum_q mask[b,q]*softmax_q(S)[k]; inv[b] ----
  if (t < 160) {
    const int b = t / 5, k = t - 5 * b;
    const float* ab = &asw[b * 25];
    float wk = 0.f;
#pragma unroll
    for (int q = 0; q < 5; ++q) {
      float s0 = ab[q * 5 + 0], s1 = ab[q * 5 + 1], s2 = ab[q * 5 + 2],
            s3 = ab[q * 5 + 3], s4 = ab[q * 5 + 4];
      float mx = fmaxf(fmaxf(fmaxf(s0, s1), fmaxf(s2, s3)), s4);
      float ps = __expf(s0 - mx) + __expf(s1 - mx) + __expf(s2 - mx) +
                 __expf(s3 - mx) + __expf(s4 - mx);
      float ek = __expf(ab[q * 5 + k] - mx);
      wk += maskLs[b * 5 + q] * __fdividef(ek, ps);
    }
    wkLs[t] = wk;
  }
  if (t < 32) {
    float msum = maskLs[t * 5] + maskLs[t * 5 + 1] + maskLs[t * 5 + 2] +
                 maskLs[t * 5 + 3] + maskLs[t * 5 + 4];
    invLs[t] = 1.0f / (msum + 1e-8f);
  }
  __syncthreads();

  // ---- phase 3a: pooled = inv * sum_k wk[k]*V[k][:], write as A-frags ---
  for (int i = t; i < 32 * 64; i += 512) {
    int b = i >> 6, d = i & 63;
    const float* wk = &wkLs[b * 5];
    float acc = 0.f;
#pragma unroll
    for (int k = 0; k < 5; ++k)
      acc = __builtin_fmaf(wk[k], b2f(Els[(5 * b + k) * ESTR + 96 + d]), acc);
    float pv = acc * invLs[b];
    unsigned short hi = f2b(pv);
    unsigned short lo = f2b(pv - b2f(hi));
    // A-frag position: frag (b>>4)*2 + (d>>5), lane ((d>>3)&3)*16 + (b&15),
    // element d&7
    int fi = (((b >> 4) * 2 + (d >> 5)) * 64 + ((d >> 3) & 3) * 16 + (b & 15)) * 8
             + (d & 7);
    pHi[fi] = hi; pLo[fi] = lo;
  }
  __syncthreads();

  // ---- phase 3b: H = gelu(pooled @ Wmlp^T + bias) via MFMA --------------
  // 16 tiles (mt 0..1, nt 0..7); wave w: mt=w>>2, nt=(w&3)*2+{0,1}.
  // H cols <64 -> split-bf16 A-frags (for 3c); cols >=64 -> f32 rows (value
  // head). All land in the now-dead Els region.
  {
    unsigned short* HHi = (unsigned short*)shpool;                 // 4,096 B
    unsigned short* HLo = (unsigned short*)(shpool + 4096);        // 4,096 B
    float* Hv = (float*)(shpool + 8192);                           // [32][65]
    const int mt = w >> 2;
    union { uint4 u; bf16x8 v; } aH0, aH1, aL0, aL1;
    aH0.u = *(const uint4*)&pHi[((mt * 2 + 0) * 64 + lane) * 8];
    aH1.u = *(const uint4*)&pHi[((mt * 2 + 1) * 64 + lane) * 8];
    aL0.u = *(const uint4*)&pLo[((mt * 2 + 0) * 64 + lane) * 8];
    aL1.u = *(const uint4*)&pLo[((mt * 2 + 1) * 64 + lane) * 8];
#pragma unroll
    for (int tI = 0; tI < 2; ++tI) {
      int nt = (w & 3) * 2 + tI;
      union { uint4 u; bf16x8 v; } b0, b1;
      b0.u = wf2[(nt * 2 + 0) * 64 + lane];
      b1.u = wf2[(nt * 2 + 1) * 64 + lane];
      f32x4 acc = {0.f, 0.f, 0.f, 0.f};
      acc = __builtin_amdgcn_mfma_f32_16x16x32_bf16(aL0.v, b0.v, acc, 0, 0, 0);
      acc = __builtin_amdgcn_mfma_f32_16x16x32_bf16(aL1.v, b1.v, acc, 0, 0, 0);
      acc = __builtin_amdgcn_mfma_f32_16x16x32_bf16(aH0.v, b0.v, acc, 0, 0, 0);
      acc = __builtin_amdgcn_mfma_f32_16x16x32_bf16(aH1.v, b1.v, acc, 0, 0, 0);
      int col = nt * 16 + l15;                 // channel c (0..127)
      float bias = (col < 64) ? bp1[col] : bh1[col - 64];
#pragma unroll
      for (int r = 0; r < 4; ++r) {
        int row = mt * 16 + quad * 4 + r;      // batch b (0..31)
        float v = acc[r] + bias;
        float g = 0.5f * v * (1.0f + erff(v * 0.70710678118654752f));
        if (col < 64) {                        // wave-uniform branch (nt<4)
          unsigned short hi = f2b(g);
          unsigned short lo = f2b(g - b2f(hi));
          int fi = ((mt * 2 + (col >> 5)) * 64 + ((col >> 3) & 3) * 16 + (row & 15)) * 8
                   + (col & 7);
          HHi[fi] = hi; HLo[fi] = lo;
        } else {
          Hv[row * 65 + (col - 64)] = g;
        }
      }
    }
  }
  __syncthreads();

  // ---- phase 3c: logits via MFMA (8 tiles, 1/wave) + value head ---------
  {
    const unsigned short* HHi = (const unsigned short*)shpool;
    const unsigned short* HLo = (const unsigned short*)(shpool + 4096);
    const float* Hv = (const float*)(shpool + 8192);
    const int mt = w >> 2, nt = w & 3;
    union { uint4 u; bf16x8 v; } aH0, aH1, aL0, aL1, b0, b1;
    aH0.u = *(const uint4*)&HHi[((mt * 2 + 0) * 64 + lane) * 8];
    aH1.u = *(const uint4*)&HHi[((mt * 2 + 1) * 64 + lane) * 8];
    aL0.u = *(const uint4*)&HLo[((mt * 2 + 0) * 64 + lane) * 8];
    aL1.u = *(const uint4*)&HLo[((mt * 2 + 1) * 64 + lane) * 8];
    b0.u = wf3[(nt * 2 + 0) * 64 + lane];
    b1.u = wf3[(nt * 2 + 1) * 64 + lane];
    f32x4 acc = {0.f, 0.f, 0.f, 0.f};
    acc = __builtin_amdgcn_mfma_f32_16x16x32_bf16(aL0.v, b0.v, acc, 0, 0, 0);
    acc = __builtin_amdgcn_mfma_f32_16x16x32_bf16(aL1.v, b1.v, acc, 0, 0, 0);
    acc = __builtin_amdgcn_mfma_f32_16x16x32_bf16(aH0.v, b0.v, acc, 0, 0, 0);
    acc = __builtin_amdgcn_mfma_f32_16x16x32_bf16(aH1.v, b1.v, acc, 0, 0, 0);
    int col = nt * 16 + l15;                   // output o (0..63, valid <50)
    if (col < 50) {
      float bias = bp2[col];
#pragma unroll
      for (int r = 0; r < 4; ++r) {
        int row = mt * 16 + quad * 4 + r;
        long gb = (long)blockIdx.x * 32 + row;
        out[gb * 50 + col] = acc[r] + bias;
      }
    }
    if (t < 32) {                              // value head: hv @ Wh2 + bh2
      float s = bh2[0];
#pragma unroll
      for (int j = 0; j < 64; ++j)
        s = __builtin_fmaf(Hv[t * 65 + j], Wh2[j], s);
      out[(long)B * 50 + (long)blockIdx.x * 32 + t] = s;
    }
  }
}

// --------------------------------------------------------------- launch ----
extern "C" void kernel_launch(void* const* d_in, const int* in_sizes, int n_in,
                              void* d_out, int out_size, void* d_ws, size_t ws_size,
                              hipStream_t stream) {
  const float* x   = (const float*)d_in[0];
  const float* Wk  = (const float*)d_in[1];
  const float* bk  = (const float*)d_in[2];
  const float* Wq  = (const float*)d_in[3];
  const float* bq  = (const float*)d_in[4];
  const float* Wv  = (const float*)d_in[5];
  const float* bv  = (const float*)d_in[6];
  const float* Wr  = (const float*)d_in[7];
  const float* br  = (const float*)d_in[8];
  const float* Wp1 = (const float*)d_in[9];
  const float* bp1 = (const float*)d_in[10];
  const float* Wp2 = (const float*)d_in[11];
  const float* bp2 = (const float*)d_in[12];
  const float* Wh1 = (const float*)d_in[13];
  const float* bh1 = (const float*)d_in[14];
  const float* Wh2 = (const float*)d_in[15];
  const float* bh2 = (const float*)d_in[16];

  int B = in_sizes[0] / 320;  // 131072

  setup_kernel<<<1, 256, 0, stream>>>(Wk, bk, Wq, bq, Wv, bv, Wr, br,
                                      Wp1, Wh1, Wp2, (char*)d_ws);
  policy_kernel<<<B / 32, 512, 0, stream>>>(x, (const char*)d_ws,
                                            bp1, bp2, bh1, bh2, Wh2,
                                            (float*)d_out, B);
}

// Round 5
// 313.856 us; speedup vs baseline: 1.6455x; 1.1088x over previous
//
#include <hip/hip_runtime.h>
#include <stdint.h>

// LightMetaPolicy fused kernel, round 9:
//  - Setup parallelized: setup_a (Wrp, 8 blocks) + setup_b (tables, 145
//    blocks). Old 1-block setup was ~60-80us of the benched time (bench-policy
//    gap ~226us tracked table size across rounds).
//  - All MFMA phases operand-SWAPPED (A=weights, B=activations, C=E^T tile):
//    lane then holds 4 CONSECUTIVE output columns of one row -> epilogues
//    become packed ds_write_b64 (was 4x ds_write_b16), bias folds into acc
//    init. A-frag of M == B-frag of M^T, so xfrag/pHi/pLo/wf1/wf2 layouts are
//    all unchanged - only mfma argument order + epilogues changed.
//  - Value head folded into phase 3c as K=128 combined head (Wcomb=[Wp2;Wh2]
//    zero-padded; o==50 is the value row). Kills the t<32 serial tail + Hv.
//  - Phase 3a vectorized over d-pairs (ds_read_b32 V reads, u32 frag writes).
//
// E LDS per agent-row: cols [0:32)=Q, [32:64)=K, [64:96)=R, [96:160)=V
//
// MFMA 16x16x32 bf16 layouts (m89-verified):
//   A: lane holds A[m=lane&15][k=quad*8+j], j=0..7  (quad=lane>>4)
//   B: lane holds B[k=quad*8+j][n=lane&15]
//   C: lane reg r holds C[row=quad*4+r][col=lane&15]

typedef __attribute__((ext_vector_type(8))) short bf16x8;
typedef __attribute__((ext_vector_type(4))) float f32x4;

#define ESTR 168   // shorts; 336B rows: 16B-aligned, 84 dwords -> 2-way banks
#define HSTR 136   // shorts; H rows 272B: 16B-aligned, 68 dwords

#define WF1_OFF 0      // phase-1 A-frags: 40 frags (10n x {hi,lo} x 2k) = 40960
#define BC_OFF  40960  // bcat f32[160] = 640
#define WF2_OFF 41600  // phase-3b A-frags: 16 frags = 16384
#define WF3_OFF 57984  // phase-3c A-frags: 16 frags (4nt x 4s, K=128) = 16384
#define BMLP_OFF 74368 // [bp1;bh1] f32[128] = 512
#define BCOMB_OFF 74880// [bp2;bh2;0..] f32[64] = 256
#define WRP_OFF 75136  // Wr@Wq f32[32*64] = 8192
// ws total: 83328 B

__device__ __forceinline__ float b2f_lo(unsigned int pk) {
  union { unsigned int i; float f; } v; v.i = pk << 16; return v.f;
}
__device__ __forceinline__ float b2f_hi(unsigned int pk) {
  union { unsigned int i; float f; } v; v.i = pk & 0xffff0000u; return v.f;
}
__device__ __forceinline__ float b2f(unsigned short u) {
  union { unsigned int i; float f; } v; v.i = ((unsigned int)u) << 16; return v.f;
}
__device__ __forceinline__ unsigned short f2b(float f) {
  union { float f; unsigned int i; } v; v.f = f;
  unsigned int u = v.i;
  return (unsigned short)((u + 0x7fffu + ((u >> 16) & 1u)) >> 16);  // RNE
}

// -------------------------------------------------------------- setup_a ----
__global__ void setup_a(const float* __restrict__ Wr,
                        const float* __restrict__ Wq,
                        char* __restrict__ ws) {
  // Wrp = Wr @ Wq  (32x64), one output per thread, 8 blocks x 256.
  int id = blockIdx.x * 256 + threadIdx.x;
  if (id >= 32 * 64) return;
  int rr = id >> 6, d = id & 63;
  float acc = 0.f;
#pragma unroll 8
  for (int m = 0; m < 32; ++m) acc += Wr[rr * 32 + m] * Wq[m * 64 + d];
  ((float*)(ws + WRP_OFF))[id] = acc;
}

// -------------------------------------------------------------- setup_b ----
__global__ void setup_b(const float* __restrict__ Wk,
                        const float* __restrict__ bk,
                        const float* __restrict__ Wq,
                        const float* __restrict__ bq,
                        const float* __restrict__ Wv,
                        const float* __restrict__ bv,
                        const float* __restrict__ Wr,
                        const float* __restrict__ br,
                        const float* __restrict__ Wp1,
                        const float* __restrict__ bp1,
                        const float* __restrict__ Wh1,
                        const float* __restrict__ bh1,
                        const float* __restrict__ Wp2,
                        const float* __restrict__ bp2,
                        const float* __restrict__ Wh2,
                        const float* __restrict__ bh2,
                        char* __restrict__ ws) {
  const float* Wrp = (const float*)(ws + WRP_OFF);
  unsigned short* wf1 = (unsigned short*)(ws + WF1_OFF);
  float* bc = (float*)(ws + BC_OFF);
  unsigned short* wf2 = (unsigned short*)(ws + WF2_OFF);
  unsigned short* wf3 = (unsigned short*)(ws + WF3_OFF);
  float* bmlp = (float*)(ws + BMLP_OFF);
  float* bcomb = (float*)(ws + BCOMB_OFF);

  int gid = blockIdx.x * 256 + threadIdx.x;
  if (gid < 20480) {
    // phase-1 A-frags, SPLIT hi/lo: frag f = n*4 + h*2 + s
    int i = gid;
    int j = i & 7, l = (i >> 3) & 63, f = i >> 9;
    int n = f >> 2, h = (f >> 1) & 1, s = f & 1;
    int r = n * 16 + (l & 15);             // output channel (Wcat row)
    int k = s * 32 + ((l >> 4) & 3) * 8 + j;
    float w;
    if (r < 32)      w = Wq[r * 64 + k];
    else if (r < 64) w = Wk[(r - 32) * 64 + k];
    else if (r < 96) w = Wrp[(r - 64) * 64 + k];
    else             w = Wv[(r - 96) * 64 + k];
    unsigned short hi = f2b(w);
    wf1[i] = h ? f2b(w - b2f(hi)) : hi;
  } else if (gid < 28672) {
    // phase-3b A-frags (Wmlp = [Wp1;Wh1], 128x64): f = cht*2+s
    int i = gid - 20480;
    int j = i & 7, l = (i >> 3) & 63, fs = i >> 9;
    int nt = fs >> 1, s = fs & 1;
    int n = nt * 16 + (l & 15);
    int k = s * 32 + ((l >> 4) & 3) * 8 + j;
    float wv = (n < 64) ? Wp1[n * 64 + k] : Wh1[(n - 64) * 64 + k];
    wf2[i] = f2b(wv);
  } else if (gid < 36864) {
    // phase-3c A-frags, combined head (Wcomb 64x128): f = nt*4 + s (s 0..3)
    int i = gid - 28672;
    int j = i & 7, l = (i >> 3) & 63, f = i >> 9;
    int nt = f >> 2, s = f & 3;
    int o = nt * 16 + (l & 15);
    int k = s * 32 + ((l >> 4) & 3) * 8 + j;
    float wv = 0.f;
    if (o < 50 && k < 64)        wv = Wp2[o * 64 + k];
    else if (o == 50 && k >= 64) wv = Wh2[k - 64];
    wf3[i] = f2b(wv);
  } else {
    int sid = gid - 36864;
    if (sid < 160) {
      int r = sid;
      float v;
      if (r < 32)      v = bq[r];
      else if (r < 64) v = bk[r - 32];
      else if (r < 96) {
        int rr = r - 64;
        float acc = br[rr];
        for (int m = 0; m < 32; ++m) acc += Wr[rr * 32 + m] * bq[m];
        v = acc;
      } else            v = bv[r - 96];
      bc[r] = v;
    } else if (sid < 288) {
      int c = sid - 160;
      bmlp[c] = (c < 64) ? bp1[c] : bh1[c - 64];
    } else if (sid < 352) {
      int o = sid - 288;
      bcomb[o] = (o < 50) ? bp2[o] : ((o == 50) ? bh2[0] : 0.f);
    }
  }
}

// ----------------------------------------------------------------- main ----
__global__ __launch_bounds__(512, 2)
void policy_kernel(const float* __restrict__ x,
                   const char* __restrict__ ws,
                   float* __restrict__ out, int B) {
  // 32 batches/block = 160 agent-rows. 8 waves.
  // LDS pool (74,880 B -> 2 blocks/CU):
  //   [0      .. 53,760)  Els 160 x ESTR bf16  (3b/3c reuse head as HHi/HLo)
  //   [53,760 .. 54,400)  maskLs f32[160]
  //   [54,400 .. 74,880)  union:
  //     phase 1 : xfrag 20 frags x 1KB = 20,480
  //     phase 2+: asw f32[800] | wkLs f32[160] | invLs f32[32] | pHi | pLo
  __shared__ __align__(16) char shpool[74880];
  unsigned short* Els = (unsigned short*)shpool;
  float* maskLs = (float*)(shpool + 53760);
  unsigned short* xfrag = (unsigned short*)(shpool + 54400);
  float* asw  = (float*)(shpool + 54400);
  float* wkLs = (float*)(shpool + 57600);
  float* invLs = (float*)(shpool + 58240);
  unsigned short* pHi = (unsigned short*)(shpool + 58368);
  unsigned short* pLo = (unsigned short*)(shpool + 62464);
  // phase-3 aliases in dead Els: HHi [32][HSTR], HLo [32][HSTR]
  unsigned short* HHi = (unsigned short*)shpool;                   // 8,704 B
  unsigned short* HLo = (unsigned short*)(shpool + 8704);          // 8,704 B

  const int t = threadIdx.x;
  const int w = t >> 6, lane = t & 63;
  const int l15 = lane & 15, quad = lane >> 4;

  const uint4* wf1 = (const uint4*)(ws + WF1_OFF);
  const float* bc = (const float*)(ws + BC_OFF);
  const uint4* wf2 = (const uint4*)(ws + WF2_OFF);
  const uint4* wf3 = (const uint4*)(ws + WF3_OFF);
  const float* bmlp = (const float*)(ws + BMLP_OFF);
  const float* bcomb = (const float*)(ws + BCOMB_OFF);

  // ---- phase 1a: convert x -> bf16 frags in LDS; fused agent mask -------
  // Lane layout per m-tile: row = m*16+l15, cols [quad*8,quad*8+8) and +32.
  for (int m = w; m < 10; m += 8) {
    long row = (long)blockIdx.x * 160 + m * 16 + l15;
    const float* xr = x + row * 64 + quad * 8;
    float xv[16];
    *(float4*)(xv + 0)  = *(const float4*)(xr);
    *(float4*)(xv + 4)  = *(const float4*)(xr + 4);
    *(float4*)(xv + 8)  = *(const float4*)(xr + 32);
    *(float4*)(xv + 12) = *(const float4*)(xr + 36);
    float ms = 0.f;
#pragma unroll
    for (int i = 0; i < 16; ++i) ms += fabsf(xv[i]);
    ms += __shfl_xor(ms, 16, 64);    // reduce across the 4 quads
    ms += __shfl_xor(ms, 32, 64);
    if (quad == 0) maskLs[m * 16 + l15] = (ms > 0.01f) ? 1.f : 0.f;
    unsigned int pk[8];
#pragma unroll
    for (int i = 0; i < 8; ++i)
      pk[i] = (unsigned int)f2b(xv[2 * i]) |
              ((unsigned int)f2b(xv[2 * i + 1]) << 16);
    *(uint4*)&xfrag[((m * 2 + 0) * 64 + lane) * 8] =
        make_uint4(pk[0], pk[1], pk[2], pk[3]);
    *(uint4*)&xfrag[((m * 2 + 1) * 64 + lane) * 8] =
        make_uint4(pk[4], pk[5], pk[6], pk[7]);
  }
  __syncthreads();

  // ---- phase 1b: E^T tiles = Wcat @ x^T (+bias init), packed b64 stores -
  // Lane holds E[agent row l15][4 consecutive channels quad*4+r].
  {
    union { uint4 u; bf16x8 v; } ah0, ah1, al0, al1, b0, b1;
    int ncur = -1;
    float4 bb = {0.f, 0.f, 0.f, 0.f};
    const int start = (w < 4) ? w * 13 : 52 + (w - 4) * 12;
    const int cnt = (w < 4) ? 13 : 12;
    for (int ti = 0; ti < cnt; ++ti) {
      int tt = start + ti;
      int n = tt / 10, m = tt - n * 10;
      if (n != ncur) {
        ncur = n;
        ah0.u = wf1[(n * 4 + 0) * 64 + lane];   // W hi, k 0..31
        ah1.u = wf1[(n * 4 + 1) * 64 + lane];   // W hi, k 32..63
        al0.u = wf1[(n * 4 + 2) * 64 + lane];   // W lo, k 0..31
        al1.u = wf1[(n * 4 + 3) * 64 + lane];   // W lo, k 32..63
        bb = *(const float4*)&bc[n * 16 + quad * 4];
      }
      b0.u = *(const uint4*)&xfrag[((m * 2 + 0) * 64 + lane) * 8];
      b1.u = *(const uint4*)&xfrag[((m * 2 + 1) * 64 + lane) * 8];
      f32x4 acc = {bb.x, bb.y, bb.z, bb.w};
      acc = __builtin_amdgcn_mfma_f32_16x16x32_bf16(ah0.v, b0.v, acc, 0, 0, 0);
      acc = __builtin_amdgcn_mfma_f32_16x16x32_bf16(ah1.v, b1.v, acc, 0, 0, 0);
      acc = __builtin_amdgcn_mfma_f32_16x16x32_bf16(al0.v, b0.v, acc, 0, 0, 0);
      acc = __builtin_amdgcn_mfma_f32_16x16x32_bf16(al1.v, b1.v, acc, 0, 0, 0);
      unsigned int u0 = (unsigned int)f2b(acc[0]) |
                        ((unsigned int)f2b(acc[1]) << 16);
      unsigned int u1 = (unsigned int)f2b(acc[2]) |
                        ((unsigned int)f2b(acc[3]) << 16);
      *(uint2*)&Els[(m * 16 + l15) * ESTR + n * 16 + quad * 4] =
          make_uint2(u0, u1);
    }
  }
  __syncthreads();

  // ---- phase 2: S = scale*(Q·K^T + R·R^T) via MFMA, 15-row windows ------
  // Tile ti covers agent rows [15ti, 15ti+16): batches 3ti..3ti+2 complete.
  // A-pattern register passed as B gives C = A @ X^T; off-diag discarded.
  for (int ti = w; ti < 11; ti += 8) {
    const unsigned short* ra = &Els[(ti * 15 + l15) * ESTR];
    union { uint4 u; bf16x8 v; } a0, a1, b0;
    a0.u = *(const uint4*)&ra[quad * 8];        // Q cols [0,32)
    b0.u = *(const uint4*)&ra[32 + quad * 8];   // K cols [32,64)
    a1.u = *(const uint4*)&ra[64 + quad * 8];   // R cols [64,96)
    f32x4 acc = {0.f, 0.f, 0.f, 0.f};
    acc = __builtin_amdgcn_mfma_f32_16x16x32_bf16(a0.v, b0.v, acc, 0, 0, 0);
    acc = __builtin_amdgcn_mfma_f32_16x16x32_bf16(a1.v, a1.v, acc, 0, 0, 0);
#pragma unroll
    for (int r = 0; r < 4; ++r) {
      int arq = ti * 15 + quad * 4 + r;   // query agent-row
      int ark = ti * 15 + l15;            // key agent-row
      int bq = arq / 5, qq = arq - 5 * bq;
      int bk2 = ark / 5, kk = ark - 5 * bk2;
      if (bq == bk2 && bq < 32)
        asw[bq * 25 + qq * 5 + kk] = acc[r] * 0.17677669529663689f;
    }
  }
  __syncthreads();

  // ---- phase 2bc: wk[b][k] = sum_q mask[b,q]*softmax_q(S)[k]; inv[b] ----
  if (t < 160) {
    const int b = t / 5, k = t - 5 * b;
    const float* ab = &asw[b * 25];
    float wk = 0.f;
#pragma unroll
    for (int q = 0; q < 5; ++q) {
      float s0 = ab[q * 5 + 0], s1 = ab[q * 5 + 1], s2 = ab[q * 5 + 2],
            s3 = ab[q * 5 + 3], s4 = ab[q * 5 + 4];
      float mx = fmaxf(fmaxf(fmaxf(s0, s1), fmaxf(s2, s3)), s4);
      float ps = __expf(s0 - mx) + __expf(s1 - mx) + __expf(s2 - mx) +
                 __expf(s3 - mx) + __expf(s4 - mx);
      float ek = __expf(ab[q * 5 + k] - mx);
      wk += maskLs[b * 5 + q] * __fdividef(ek, ps);
    }
    wkLs[t] = wk;
  }
  if (t < 32) {
    float msum = maskLs[t * 5] + maskLs[t * 5 + 1] + maskLs[t * 5 + 2] +
                 maskLs[t * 5 + 3] + maskLs[t * 5 + 4];
    invLs[t] = 1.0f / (msum + 1e-8f);
  }
  __syncthreads();

  // ---- phase 3a: pooled = inv * sum_k wk[k]*V[k][:], d-pairs, u32 writes -
  for (int i = t; i < 32 * 32; i += 512) {
    int b = i >> 5, d0 = (i & 31) * 2;
    const float* wk = &wkLs[b * 5];
    float a0 = 0.f, a1 = 0.f;
#pragma unroll
    for (int k = 0; k < 5; ++k) {
      unsigned int v = *(const unsigned int*)&Els[(5 * b + k) * ESTR + 96 + d0];
      a0 = __builtin_fmaf(wk[k], b2f_lo(v), a0);
      a1 = __builtin_fmaf(wk[k], b2f_hi(v), a1);
    }
    float inv = invLs[b];
    float p0 = a0 * inv, p1 = a1 * inv;
    unsigned short h0 = f2b(p0), h1 = f2b(p1);
    unsigned short l0 = f2b(p0 - b2f(h0)), l1 = f2b(p1 - b2f(h1));
    // frag layout (A of pooled == B of pooled^T): frag (b>>4)*2+(d>>5),
    // lane ((d>>3)&3)*16 + (b&15), elem d&7; d0 even -> u32-packable.
    int fi = (((b >> 4) * 2 + (d0 >> 5)) * 64 + ((d0 >> 3) & 3) * 16 + (b & 15))
                 * 8 + (d0 & 7);
    *(unsigned int*)&pHi[fi] = (unsigned int)h0 | ((unsigned int)h1 << 16);
    *(unsigned int*)&pLo[fi] = (unsigned int)l0 | ((unsigned int)l1 << 16);
  }
  __syncthreads();

  // ---- phase 3b: H^T tiles = Wmlp @ pooled^T (+bias), gelu, b64 stores --
  // Lane holds H[batch l15][4 consecutive channels]; all 128 ch -> hi/lo
  // frags row-major in dead-Els (HHi/HLo), feeding 3c as B-frags.
  {
    const int mt = w >> 2;
    union { uint4 u; bf16x8 v; } pH0, pH1, pL0, pL1;
    pH0.u = *(const uint4*)&pHi[((mt * 2 + 0) * 64 + lane) * 8];
    pH1.u = *(const uint4*)&pHi[((mt * 2 + 1) * 64 + lane) * 8];
    pL0.u = *(const uint4*)&pLo[((mt * 2 + 0) * 64 + lane) * 8];
    pL1.u = *(const uint4*)&pLo[((mt * 2 + 1) * 64 + lane) * 8];
#pragma unroll
    for (int tI = 0; tI < 2; ++tI) {
      int cht = (w & 3) * 2 + tI;
      union { uint4 u; bf16x8 v; } aw0, aw1;
      aw0.u = wf2[(cht * 2 + 0) * 64 + lane];
      aw1.u = wf2[(cht * 2 + 1) * 64 + lane];
      float4 bb = *(const float4*)&bmlp[cht * 16 + quad * 4];
      f32x4 acc = {bb.x, bb.y, bb.z, bb.w};
      acc = __builtin_amdgcn_mfma_f32_16x16x32_bf16(aw0.v, pH0.v, acc, 0, 0, 0);
      acc = __builtin_amdgcn_mfma_f32_16x16x32_bf16(aw1.v, pH1.v, acc, 0, 0, 0);
      acc = __builtin_amdgcn_mfma_f32_16x16x32_bf16(aw0.v, pL0.v, acc, 0, 0, 0);
      acc = __builtin_amdgcn_mfma_f32_16x16x32_bf16(aw1.v, pL1.v, acc, 0, 0, 0);
      unsigned short hi[4], lo[4];
#pragma unroll
      for (int r = 0; r < 4; ++r) {
        float v = acc[r];
        float g = 0.5f * v * (1.0f + erff(v * 0.70710678118654752f));
        hi[r] = f2b(g);
        lo[r] = f2b(g - b2f(hi[r]));
      }
      int base = (mt * 16 + l15) * HSTR + cht * 16 + quad * 4;
      *(uint2*)&HHi[base] = make_uint2(
          (unsigned int)hi[0] | ((unsigned int)hi[1] << 16),
          (unsigned int)hi[2] | ((unsigned int)hi[3] << 16));
      *(uint2*)&HLo[base] = make_uint2(
          (unsigned int)lo[0] | ((unsigned int)lo[1] << 16),
          (unsigned int)lo[2] | ((unsigned int)lo[3] << 16));
    }
  }
  __syncthreads();

  // ---- phase 3c: out^T tiles = Wcomb @ H^T (K=128), logits + value ------
  {
    const int mt = w >> 2, nt = w & 3;
    const int row = mt * 16 + l15;            // batch (0..31)
    union { uint4 u; bf16x8 v; } a[4], bh[4], bl[4];
#pragma unroll
    for (int s = 0; s < 4; ++s) {
      a[s].u = wf3[(nt * 4 + s) * 64 + lane];
      bh[s].u = *(const uint4*)&HHi[row * HSTR + s * 32 + quad * 8];
      bl[s].u = *(const uint4*)&HLo[row * HSTR + s * 32 + quad * 8];
    }
    float4 bb = *(const float4*)&bcomb[nt * 16 + quad * 4];
    f32x4 acc = {bb.x, bb.y, bb.z, bb.w};
#pragma unroll
    for (int s = 0; s < 4; ++s) {
      acc = __builtin_amdgcn_mfma_f32_16x16x32_bf16(a[s].v, bh[s].v, acc, 0, 0, 0);
      acc = __builtin_amdgcn_mfma_f32_16x16x32_bf16(a[s].v, bl[s].v, acc, 0, 0, 0);
    }
    long gb = (long)blockIdx.x * 32 + row;
    int o0 = nt * 16 + quad * 4;
#pragma unroll
    for (int r = 0; r < 4; ++r) {
      int o = o0 + r;
      if (o < 50)       out[gb * 50 + o] = acc[r];
      else if (o == 50) out[(long)B * 50 + gb] = acc[r];
    }
  }
}

// --------------------------------------------------------------- launch ----
extern "C" void kernel_launch(void* const* d_in, const int* in_sizes, int n_in,
                              void* d_out, int out_size, void* d_ws, size_t ws_size,
                              hipStream_t stream) {
  const float* x   = (const float*)d_in[0];
  const float* Wk  = (const float*)d_in[1];
  const float* bk  = (const float*)d_in[2];
  const float* Wq  = (const float*)d_in[3];
  const float* bq  = (const float*)d_in[4];
  const float* Wv  = (const float*)d_in[5];
  const float* bv  = (const float*)d_in[6];
  const float* Wr  = (const float*)d_in[7];
  const float* br  = (const float*)d_in[8];
  const float* Wp1 = (const float*)d_in[9];
  const float* bp1 = (const float*)d_in[10];
  const float* Wp2 = (const float*)d_in[11];
  const float* bp2 = (const float*)d_in[12];
  const float* Wh1 = (const float*)d_in[13];
  const float* bh1 = (const float*)d_in[14];
  const float* Wh2 = (const float*)d_in[15];
  const float* bh2 = (const float*)d_in[16];

  int B = in_sizes[0] / 320;  // 131072

  setup_a<<<8, 256, 0, stream>>>(Wr, Wq, (char*)d_ws);
  setup_b<<<145, 256, 0, stream>>>(Wk, bk, Wq, bq, Wv, bv, Wr, br,
                                   Wp1, bp1, Wh1, bh1, Wp2, bp2, Wh2, bh2,
                                   (char*)d_ws);
  policy_kernel<<<B / 32, 512, 0, stream>>>(x, (const char*)d_ws,
                                            (float*)d_out, B);
}

// Round 7
// 299.894 us; speedup vs baseline: 1.7221x; 1.0466x over previous
//
#include <hip/hip_runtime.h>
#include <stdint.h>

// LightMetaPolicy fused kernel, round 10.1 — algebraic collapse, bisected:
//  - KEEP from r10: softmax shift-invariance (S_qk = G_q . x_k, G = X@(s·M)+s·v,
//    M = Wq^T Wk + Wrq^T Wrq precomputed); Wv folded into MLP (Wfold = Wmlp@Wv,
//    u = Wmlp·bv; V never materialized); LDS 50.7K -> 3 blocks/CU; Wcomb hi/lo.
//  - REVERT (NaN bisect): v_cvt_pk_bf16_f32 asm -> proven f2b scalar packing
//    (suspect: 16-bit-dest semantics leaving junk hi-16 -> Inf/NaN bf16 into
//    MFMA; also m240: asm cvt_pk is slower than scalar casts anyway);
//    tanh-gelu -> proven exact erff; launch_bounds (512,3) -> proven (512,2)
//    (VGPR ~52 anyway; LDS alone admits 3 blocks/CU).
//  - Phase-2 row reads clamped to 159 (ti=10 lanes were reading past gfrag).
//
// MFMA 16x16x32 bf16 layouts (m89-verified):
//   A: lane holds A[m=lane&15][k=quad*8+j], j=0..7  (quad=lane>>4)
//   B: lane holds B[k=quad*8+j][n=lane&15]
//   C: lane reg r holds C[row=quad*4+r][col=lane&15]
// A-pattern register passed as B gives C = A @ X^T (swap trick).

typedef __attribute__((ext_vector_type(8))) short bf16x8;
typedef __attribute__((ext_vector_type(4))) float f32x4;

#define HSTR 136   // H rows: 272B, 16B-aligned, 68 dwords -> 2-way banks
#define SCALE 0.17677669529663689f

#define WRQ_OFF 0       // Wr@Wq f32[32*64]            = 8192
#define WF1_OFF 8192    // G-weight frags 16x1KB        = 16384
#define BCG_OFF 24576   // scale*v f32[64]              = 256
#define WF2_OFF 24832   // Wfold frags 16x1KB           = 16384
#define UV_OFF  41216   // u=[Wp1 bv;Wh1 bv] f32[128]   = 512
#define WF3_OFF 41728   // Wcomb hi/lo frags 32x1KB     = 32768
#define BMLP_OFF 74496  // [bp1;bh1] f32[128]           = 512
#define BCOMB_OFF 75008 // [bp2;bh2;0] f32[64]          = 256
// ws total: 75264 B

__device__ __forceinline__ float b2f_lo(unsigned int pk) {
  union { unsigned int i; float f; } v; v.i = pk << 16; return v.f;
}
__device__ __forceinline__ float b2f_hi(unsigned int pk) {
  union { unsigned int i; float f; } v; v.i = pk & 0xffff0000u; return v.f;
}
__device__ __forceinline__ float b2f(unsigned short u) {
  union { unsigned int i; float f; } v; v.i = ((unsigned int)u) << 16; return v.f;
}
__device__ __forceinline__ unsigned short f2b(float f) {
  union { float f; unsigned int i; } v; v.f = f;
  unsigned int u = v.i;
  return (unsigned short)((u + 0x7fffu + ((u >> 16) & 1u)) >> 16);  // RNE
}
__device__ __forceinline__ unsigned int pack2(float a, float b) {
  return (unsigned int)f2b(a) | ((unsigned int)f2b(b) << 16);
}
__device__ __forceinline__ float gelu_e(float v) {
  return 0.5f * v * (1.0f + erff(v * 0.70710678118654752f));  // exact
}

// -------------------------------------------------------------- setup_a ----
__global__ void setup_a(const float* __restrict__ Wr,
                        const float* __restrict__ Wq,
                        char* __restrict__ ws) {
  int id = blockIdx.x * 256 + threadIdx.x;
  if (id >= 32 * 64) return;
  int rr = id >> 6, d = id & 63;
  float acc = 0.f;
#pragma unroll 8
  for (int m = 0; m < 32; ++m) acc += Wr[rr * 32 + m] * Wq[m * 64 + d];
  ((float*)(ws + WRQ_OFF))[id] = acc;
}

// -------------------------------------------------------------- setup_b ----
__global__ void setup_b(const float* __restrict__ Wk,
                        const float* __restrict__ bk,
                        const float* __restrict__ Wq,
                        const float* __restrict__ bq,
                        const float* __restrict__ Wv,
                        const float* __restrict__ bv,
                        const float* __restrict__ Wr,
                        const float* __restrict__ br,
                        const float* __restrict__ Wp1,
                        const float* __restrict__ bp1,
                        const float* __restrict__ Wh1,
                        const float* __restrict__ bh1,
                        const float* __restrict__ Wp2,
                        const float* __restrict__ bp2,
                        const float* __restrict__ Wh2,
                        const float* __restrict__ bh2,
                        char* __restrict__ ws) {
  const float* Wrq = (const float*)(ws + WRQ_OFF);
  unsigned short* wf1 = (unsigned short*)(ws + WF1_OFF);
  float* bcG = (float*)(ws + BCG_OFF);
  unsigned short* wf2 = (unsigned short*)(ws + WF2_OFF);
  float* uvec = (float*)(ws + UV_OFF);
  unsigned short* wf3 = (unsigned short*)(ws + WF3_OFF);
  float* bmlp = (float*)(ws + BMLP_OFF);
  float* bcomb = (float*)(ws + BCOMB_OFF);

  int gid = blockIdx.x * 256 + threadIdx.x;
  if (gid < 8192) {
    // G-weight frags: Wg[d][e] = M[e][d], M = Wq^T Wk + Wrq^T Wrq; x SCALE.
    // f = n*4 + h*2 + s  (n 0..3 out-tile, h 0=hi 1=lo, s k-half)
    int i = gid;
    int j = i & 7, l = (i >> 3) & 63, f = i >> 9;
    int n = f >> 2, h = (f >> 1) & 1, s = f & 1;
    int d = n * 16 + (l & 15);
    int e = s * 32 + ((l >> 4) & 3) * 8 + j;
    float acc = 0.f;
    for (int m = 0; m < 32; ++m)
      acc += Wq[m * 64 + e] * Wk[m * 64 + d] +
             Wrq[m * 64 + e] * Wrq[m * 64 + d];
    float wv = acc * SCALE;
    unsigned short hi = f2b(wv);
    wf1[i] = h ? f2b(wv - b2f(hi)) : hi;
  } else if (gid < 8256) {
    // bcG[d] = SCALE * (Wk^T bq + Wrq^T brr)[d], brr = br + Wr bq
    int d = gid - 8192;
    float acc = 0.f;
    for (int m = 0; m < 32; ++m) {
      float brr = br[m];
      for (int j2 = 0; j2 < 32; ++j2) brr += Wr[m * 32 + j2] * bq[j2];
      acc += Wk[m * 64 + d] * bq[m] + Wrq[m * 64 + d] * brr;
    }
    bcG[d] = acc * SCALE;
  } else if (gid < 16448) {
    // Wfold frags: Wfold[c][e] = sum_d Wmlp[c][d] Wv[d][e]; f = cht*2+s
    int i = gid - 8256;
    int j = i & 7, l = (i >> 3) & 63, f = i >> 9;
    int cht = f >> 1, s = f & 1;
    int c = cht * 16 + (l & 15);
    int e = s * 32 + ((l >> 4) & 3) * 8 + j;
    float acc = 0.f;
    for (int d = 0; d < 64; ++d) {
      float wm = (c < 64) ? Wp1[c * 64 + d] : Wh1[(c - 64) * 64 + d];
      acc += wm * Wv[d * 64 + e];
    }
    wf2[i] = f2b(acc);
  } else if (gid < 16576) {
    // uvec[c] = Wmlp[c] . bv
    int c = gid - 16448;
    float acc = 0.f;
    for (int d = 0; d < 64; ++d) {
      float wm = (c < 64) ? Wp1[c * 64 + d] : Wh1[(c - 64) * 64 + d];
      acc += wm * bv[d];
    }
    uvec[c] = acc;
  } else if (gid < 32960) {
    // Wcomb hi/lo frags (64x128, K=128): f = nt*8 + s*2 + h
    int i = gid - 16576;
    int j = i & 7, l = (i >> 3) & 63, f = i >> 9;
    int nt = f >> 3, s = (f >> 1) & 3, h = f & 1;
    int o = nt * 16 + (l & 15);
    int k = s * 32 + ((l >> 4) & 3) * 8 + j;
    float wv = 0.f;
    if (o < 50 && k < 64)        wv = Wp2[o * 64 + k];
    else if (o == 50 && k >= 64) wv = Wh2[k - 64];
    unsigned short hi = f2b(wv);
    wf3[i] = h ? f2b(wv - b2f(hi)) : hi;
  } else if (gid < 33088) {
    int c = gid - 32960;
    bmlp[c] = (c < 64) ? bp1[c] : bh1[c - 64];
  } else if (gid < 33152) {
    int o = gid - 33088;
    bcomb[o] = (o < 50) ? bp2[o] : ((o == 50) ? bh2[0] : 0.f);
  }
}

// ----------------------------------------------------------------- main ----
__global__ __launch_bounds__(512, 2)
void policy_kernel(const float* __restrict__ x,
                   const char* __restrict__ ws,
                   float* __restrict__ out, int B) {
  // 32 batches/block = 160 agent-rows. 8 waves. LDS 50,688 B -> 3 blocks/CU.
  //   [0     ..20480)  xfrag  20 frags (X, A-pattern)      live 1a -> 3a
  //   [20480 ..40960)  gfrag  20 frags (G, A-pattern)      live 1b -> 2
  //                    HHi @20480 [32][HSTR], HLo @29184   live 3b -> 3c
  //   [40960 ..41600)  maskLs f32[160]
  //   [41600 ..49792)  union: asw f32[800] (2->2bc) | pXHi/pXLo (3a->3b)
  //   [49792 ..50688)  wkLs f32[160] | invLs f32[32] | skLs f32[32]
  __shared__ __align__(16) char shpool[50688];
  unsigned short* xfrag = (unsigned short*)shpool;
  unsigned short* gfrag = (unsigned short*)(shpool + 20480);
  float* maskLs = (float*)(shpool + 40960);
  float* asw = (float*)(shpool + 41600);
  unsigned short* pXHi = (unsigned short*)(shpool + 41600);
  unsigned short* pXLo = (unsigned short*)(shpool + 45696);
  float* wkLs  = (float*)(shpool + 49792);
  float* invLs = (float*)(shpool + 50432);
  float* skLs  = (float*)(shpool + 50560);
  unsigned short* HHi = (unsigned short*)(shpool + 20480);
  unsigned short* HLo = (unsigned short*)(shpool + 29184);

  const int t = threadIdx.x;
  const int w = t >> 6, lane = t & 63;
  const int l15 = lane & 15, quad = lane >> 4;

  // ---- phase 1a: x -> bf16 A-frags in LDS; fused agent mask -------------
  for (int m = w; m < 10; m += 8) {
    long row = (long)blockIdx.x * 160 + m * 16 + l15;
    const float* xr = x + row * 64 + quad * 8;
    float xv[16];
    *(float4*)(xv + 0)  = *(const float4*)(xr);
    *(float4*)(xv + 4)  = *(const float4*)(xr + 4);
    *(float4*)(xv + 8)  = *(const float4*)(xr + 32);
    *(float4*)(xv + 12) = *(const float4*)(xr + 36);
    float ms = 0.f;
#pragma unroll
    for (int i = 0; i < 16; ++i) ms += fabsf(xv[i]);
    ms += __shfl_xor(ms, 16, 64);
    ms += __shfl_xor(ms, 32, 64);
    if (quad == 0) maskLs[m * 16 + l15] = (ms > 0.01f) ? 1.f : 0.f;
    unsigned int pk[8];
#pragma unroll
    for (int i = 0; i < 8; ++i) pk[i] = pack2(xv[2 * i], xv[2 * i + 1]);
    *(uint4*)&xfrag[((m * 2 + 0) * 64 + lane) * 8] =
        make_uint4(pk[0], pk[1], pk[2], pk[3]);
    *(uint4*)&xfrag[((m * 2 + 1) * 64 + lane) * 8] =
        make_uint4(pk[4], pk[5], pk[6], pk[7]);
  }
  __syncthreads();

  // ---- phase 1b: G^T tiles = Wg @ X^T (+bias); wave w: n=w>>1, 5 m-tiles -
  {
    const int n = w >> 1;
    const uint4* wf1 = (const uint4*)(ws + WF1_OFF);
    const float* bcG = (const float*)(ws + BCG_OFF);
    union { uint4 u; bf16x8 v; } wh0, wh1, wl0, wl1, b0, b1;
    wh0.u = wf1[(n * 4 + 0) * 64 + lane];
    wh1.u = wf1[(n * 4 + 1) * 64 + lane];
    wl0.u = wf1[(n * 4 + 2) * 64 + lane];
    wl1.u = wf1[(n * 4 + 3) * 64 + lane];
    float4 bb = *(const float4*)&bcG[n * 16 + quad * 4];
    const int c0 = n * 16 + quad * 4;
    const int gb0 = ((c0 >> 5) * 64 + ((c0 >> 3) & 3) * 16 + l15) * 8 + (c0 & 7);
#pragma unroll
    for (int mi = 0; mi < 5; ++mi) {
      int m = (w & 1) * 5 + mi;
      b0.u = *(const uint4*)&xfrag[((m * 2 + 0) * 64 + lane) * 8];
      b1.u = *(const uint4*)&xfrag[((m * 2 + 1) * 64 + lane) * 8];
      f32x4 acc = {bb.x, bb.y, bb.z, bb.w};
      acc = __builtin_amdgcn_mfma_f32_16x16x32_bf16(wh0.v, b0.v, acc, 0, 0, 0);
      acc = __builtin_amdgcn_mfma_f32_16x16x32_bf16(wh1.v, b1.v, acc, 0, 0, 0);
      acc = __builtin_amdgcn_mfma_f32_16x16x32_bf16(wl0.v, b0.v, acc, 0, 0, 0);
      acc = __builtin_amdgcn_mfma_f32_16x16x32_bf16(wl1.v, b1.v, acc, 0, 0, 0);
      *(uint2*)&gfrag[m * 1024 + gb0] =
          make_uint2(pack2(acc[0], acc[1]), pack2(acc[2], acc[3]));
    }
  }
  __syncthreads();

  // ---- phase 2: S = G @ X^T via MFMA, 15-row windows (3 batches each) ---
  for (int ti = w; ti < 11; ti += 8) {
    int r = ti * 15 + l15;
    if (r > 159) r = 159;                    // clamp: data discarded anyway
    int fo = (r >> 4) * 1024 + quad * 128 + (r & 15) * 8;
    union { uint4 u; bf16x8 v; } a0, a1, b0, b1;
    a0.u = *(const uint4*)&gfrag[fo];
    a1.u = *(const uint4*)&gfrag[fo + 512];
    b0.u = *(const uint4*)&xfrag[fo];
    b1.u = *(const uint4*)&xfrag[fo + 512];
    f32x4 acc = {0.f, 0.f, 0.f, 0.f};
    acc = __builtin_amdgcn_mfma_f32_16x16x32_bf16(a0.v, b0.v, acc, 0, 0, 0);
    acc = __builtin_amdgcn_mfma_f32_16x16x32_bf16(a1.v, b1.v, acc, 0, 0, 0);
    int wbk = (13 * l15) >> 6, kk = l15 - 5 * wbk;  // key window-batch, idx
    bool kval = (l15 < 15);
#pragma unroll
    for (int rr = 0; rr < 4; ++rr) {
      int lr = quad * 4 + rr;
      int wb = (13 * lr) >> 6, qq = lr - 5 * wb;
      int b = ti * 3 + wb;
      if (lr < 15 && kval && wb == wbk && b < 32)
        asw[b * 25 + qq * 5 + kk] = acc[rr];
    }
  }
  __syncthreads();

  // ---- phase 2bc: wk[b][k], inv[b], skb[b]=msum*inv ---------------------
  if (t < 160) {
    const int b = t / 5, k = t - 5 * b;
    const float* ab = &asw[b * 25];
    float wk = 0.f;
#pragma unroll
    for (int q = 0; q < 5; ++q) {
      float s0 = ab[q * 5 + 0], s1 = ab[q * 5 + 1], s2 = ab[q * 5 + 2],
            s3 = ab[q * 5 + 3], s4 = ab[q * 5 + 4];
      float mx = fmaxf(fmaxf(fmaxf(s0, s1), fmaxf(s2, s3)), s4);
      float ps = __expf(s0 - mx) + __expf(s1 - mx) + __expf(s2 - mx) +
                 __expf(s3 - mx) + __expf(s4 - mx);
      float ek = __expf(ab[q * 5 + k] - mx);
      wk += maskLs[b * 5 + q] * __fdividef(ek, ps);
    }
    wkLs[t] = wk;
  }
  if (t < 32) {
    float msum = maskLs[t * 5] + maskLs[t * 5 + 1] + maskLs[t * 5 + 2] +
                 maskLs[t * 5 + 3] + maskLs[t * 5 + 4];
    float inv = 1.0f / (msum + 1e-8f);
    invLs[t] = inv;
    skLs[t] = msum * inv;
  }
  __syncthreads();

  // ---- phase 3a: xpool = inv * sum_k wk[k]*X[5b+k], split hi/lo frags ---
  for (int i = t; i < 32 * 32; i += 512) {
    int b = i >> 5, d0 = (i & 31) * 2;
    const float* wk = &wkLs[b * 5];
    float a0 = 0.f, a1 = 0.f;
#pragma unroll
    for (int k = 0; k < 5; ++k) {
      int rr = 5 * b + k;
      int ad = ((rr >> 4) * 2 + (d0 >> 5)) * 512 + ((d0 >> 3) & 3) * 128 +
               (rr & 15) * 8 + (d0 & 7);
      unsigned int v = *(const unsigned int*)&xfrag[ad];
      a0 = __builtin_fmaf(wk[k], b2f_lo(v), a0);
      a1 = __builtin_fmaf(wk[k], b2f_hi(v), a1);
    }
    float inv = invLs[b];
    float p0 = a0 * inv, p1 = a1 * inv;
    unsigned short h0 = f2b(p0), h1 = f2b(p1);
    float r0 = p0 - b2f(h0), r1 = p1 - b2f(h1);
    int fi = (((b >> 4) * 2 + (d0 >> 5)) * 64 + ((d0 >> 3) & 3) * 16 + (b & 15))
                 * 8 + (d0 & 7);
    *(unsigned int*)&pXHi[fi] = (unsigned int)h0 | ((unsigned int)h1 << 16);
    *(unsigned int*)&pXLo[fi] = pack2(r0, r1);
  }
  __syncthreads();

  // ---- phase 3b: H^T = Wfold @ xpool^T + (bmlp + skb*u), exact gelu -----
  {
    const int mt = w >> 2;
    const uint4* wf2 = (const uint4*)(ws + WF2_OFF);
    const float* bmlp = (const float*)(ws + BMLP_OFF);
    const float* uvec = (const float*)(ws + UV_OFF);
    union { uint4 u; bf16x8 v; } pH0, pH1, pL0, pL1, aw0, aw1;
    pH0.u = *(const uint4*)&pXHi[((mt * 2 + 0) * 64 + lane) * 8];
    pH1.u = *(const uint4*)&pXHi[((mt * 2 + 1) * 64 + lane) * 8];
    pL0.u = *(const uint4*)&pXLo[((mt * 2 + 0) * 64 + lane) * 8];
    pL1.u = *(const uint4*)&pXLo[((mt * 2 + 1) * 64 + lane) * 8];
    float skb = skLs[mt * 16 + l15];
#pragma unroll
    for (int tI = 0; tI < 2; ++tI) {
      int cht = (w & 3) * 2 + tI;
      aw0.u = wf2[(cht * 2 + 0) * 64 + lane];
      aw1.u = wf2[(cht * 2 + 1) * 64 + lane];
      float4 bm = *(const float4*)&bmlp[cht * 16 + quad * 4];
      float4 uu = *(const float4*)&uvec[cht * 16 + quad * 4];
      f32x4 acc = {__builtin_fmaf(skb, uu.x, bm.x),
                   __builtin_fmaf(skb, uu.y, bm.y),
                   __builtin_fmaf(skb, uu.z, bm.z),
                   __builtin_fmaf(skb, uu.w, bm.w)};
      acc = __builtin_amdgcn_mfma_f32_16x16x32_bf16(aw0.v, pH0.v, acc, 0, 0, 0);
      acc = __builtin_amdgcn_mfma_f32_16x16x32_bf16(aw1.v, pH1.v, acc, 0, 0, 0);
      acc = __builtin_amdgcn_mfma_f32_16x16x32_bf16(aw0.v, pL0.v, acc, 0, 0, 0);
      acc = __builtin_amdgcn_mfma_f32_16x16x32_bf16(aw1.v, pL1.v, acc, 0, 0, 0);
      unsigned short hi[4], lo[4];
#pragma unroll
      for (int r = 0; r < 4; ++r) {
        float g = gelu_e(acc[r]);
        hi[r] = f2b(g);
        lo[r] = f2b(g - b2f(hi[r]));
      }
      int base = (mt * 16 + l15) * HSTR + cht * 16 + quad * 4;
      *(uint2*)&HHi[base] = make_uint2(
          (unsigned int)hi[0] | ((unsigned int)hi[1] << 16),
          (unsigned int)hi[2] | ((unsigned int)hi[3] << 16));
      *(uint2*)&HLo[base] = make_uint2(
          (unsigned int)lo[0] | ((unsigned int)lo[1] << 16),
          (unsigned int)lo[2] | ((unsigned int)lo[3] << 16));
    }
  }
  __syncthreads();

  // ---- phase 3c: out^T = Wcomb(hi/lo) @ H^T (K=128), logits + value -----
  {
    const int mt = w >> 2, nt = w & 3;
    const int row = mt * 16 + l15;  // batch
    const uint4* wf3 = (const uint4*)(ws + WF3_OFF);
    const float* bcomb = (const float*)(ws + BCOMB_OFF);
    float4 bb = *(const float4*)&bcomb[nt * 16 + quad * 4];
    f32x4 acc = {bb.x, bb.y, bb.z, bb.w};
    union { uint4 u; bf16x8 v; } ah, al, bh, bl;
#pragma unroll
    for (int s = 0; s < 4; ++s) {
      ah.u = wf3[(nt * 8 + s * 2 + 0) * 64 + lane];
      al.u = wf3[(nt * 8 + s * 2 + 1) * 64 + lane];
      bh.u = *(const uint4*)&HHi[row * HSTR + s * 32 + quad * 8];
      bl.u = *(const uint4*)&HLo[row * HSTR + s * 32 + quad * 8];
      acc = __builtin_amdgcn_mfma_f32_16x16x32_bf16(ah.v, bh.v, acc, 0, 0, 0);
      acc = __builtin_amdgcn_mfma_f32_16x16x32_bf16(ah.v, bl.v, acc, 0, 0, 0);
      acc = __builtin_amdgcn_mfma_f32_16x16x32_bf16(al.v, bh.v, acc, 0, 0, 0);
    }
    long gb = (long)blockIdx.x * 32 + row;
    int o0 = nt * 16 + quad * 4;
#pragma unroll
    for (int rr = 0; rr < 4; ++rr) {
      int o = o0 + rr;
      if (o < 50)       out[gb * 50 + o] = acc[rr];
      else if (o == 50) out[(long)B * 50 + gb] = acc[rr];
    }
  }
}

// --------------------------------------------------------------- launch ----
extern "C" void kernel_launch(void* const* d_in, const int* in_sizes, int n_in,
                              void* d_out, int out_size, void* d_ws, size_t ws_size,
                              hipStream_t stream) {
  const float* x   = (const float*)d_in[0];
  const float* Wk  = (const float*)d_in[1];
  const float* bk  = (const float*)d_in[2];
  const float* Wq  = (const float*)d_in[3];
  const float* bq  = (const float*)d_in[4];
  const float* Wv  = (const float*)d_in[5];
  const float* bv  = (const float*)d_in[6];
  const float* Wr  = (const float*)d_in[7];
  const float* br  = (const float*)d_in[8];
  const float* Wp1 = (const float*)d_in[9];
  const float* bp1 = (const float*)d_in[10];
  const float* Wp2 = (const float*)d_in[11];
  const float* bp2 = (const float*)d_in[12];
  const float* Wh1 = (const float*)d_in[13];
  const float* bh1 = (const float*)d_in[14];
  const float* Wh2 = (const float*)d_in[15];
  const float* bh2 = (const float*)d_in[16];

  int B = in_sizes[0] / 320;  // 131072

  setup_a<<<8, 256, 0, stream>>>(Wr, Wq, (char*)d_ws);
  setup_b<<<130, 256, 0, stream>>>(Wk, bk, Wq, bq, Wv, bv, Wr, br,
                                   Wp1, bp1, Wh1, bh1, Wp2, bp2, Wh2, bh2,
                                   (char*)d_ws);
  policy_kernel<<<B / 32, 512, 0, stream>>>(x, (const char*)d_ws,
                                            (float*)d_out, B);
}